// Round 14
// baseline (121.187 us; speedup 1.0000x reference)
//
#include <hip/hip_runtime.h>
#include <hip/hip_bf16.h>
#include <math.h>

#define C_DIM 512
#define N_DIM 2048
#define B_DIM 4
#define NGRP 32
#define GCH 16          // channels per group
#define NHEAD 8
#define HDIM 64
#define EPSV 1e-6f

using f32x4  = __attribute__((ext_vector_type(4))) float;
using bf16x8 = __attribute__((ext_vector_type(8))) short;   // 8 bf16 raw bits (4 VGPRs)

// async global->LDS, 16B per lane; LDS dest = wave-uniform base + lane*16
#define GLL16(gp, lp) __builtin_amdgcn_global_load_lds( \
    (const __attribute__((address_space(1))) unsigned int*)(gp), \
    (__attribute__((address_space(3))) unsigned int*)(lp), 16, 0, 0)

// pack high-16 (truncated bf16) of two f32s: lo16 = a, hi16 = b
#define BFPACK(a, b) __builtin_amdgcn_perm(__float_as_uint(b), __float_as_uint(a), 0x07060302u)

static __device__ __forceinline__ unsigned short f2bf(float f) {
    union { __hip_bfloat16 h; unsigned short u; } cv;
    cv.h = __float2bfloat16(f);
    return cv.u;
}

// ---------------------------------------------------------------------------
// gn_stats: 2 blocks per (b,group) half-slab; partial sums.
// ---------------------------------------------------------------------------
__global__ __launch_bounds__(256) void gn_stats(const float* __restrict__ x,
                                                float* __restrict__ partial) {
    const int HSZ = GCH * N_DIM / 2;        // 16384 floats per half
    int blk = blockIdx.x;                   // 0..255
    const float4* x4 = (const float4*)(x + (size_t)blk * HSZ);
    int tid = threadIdx.x;

    float s = 0.f, ss = 0.f;
    #pragma unroll
    for (int it = 0; it < HSZ / 4 / 256; ++it) {
        float4 v = x4[tid + it * 256];
        s  += v.x + v.y + v.z + v.w;
        ss += v.x * v.x + v.y * v.y + v.z * v.z + v.w * v.w;
    }
    __shared__ float rs[256], rss[256];
    rs[tid] = s; rss[tid] = ss;
    __syncthreads();
    for (int off = 128; off > 0; off >>= 1) {
        if (tid < off) { rs[tid] += rs[tid + off]; rss[tid] += rss[tid + off]; }
        __syncthreads();
    }
    if (tid == 0) {
        partial[blk * 2]     = rs[0];
        partial[blk * 2 + 1] = rss[0];
    }
}

// ---------------------------------------------------------------------------
// gn_apply_t: x [b][c][n] fp32 -> ht [(b*n)][c] bf16 (normalized, transposed).
// ---------------------------------------------------------------------------
__global__ __launch_bounds__(256) void gn_apply_t(const float* __restrict__ x,
                                                  const float* __restrict__ partial,
                                                  const float* __restrict__ gamma,
                                                  const float* __restrict__ beta,
                                                  unsigned short* __restrict__ ht) {
    __shared__ char smem[8192];     // [64 n][64 c] bf16, rows 128B, XOR-swizzled
    const float GSZI = 1.f / (GCH * N_DIM);
    int n0 = blockIdx.x * 64, c0 = blockIdx.y * 64, b = blockIdx.z;
    int tid = threadIdx.x;
    #pragma unroll
    for (int it = 0; it < 4; ++it) {
        int idx = tid + it * 256;
        int ci = idx >> 4, n4 = (idx & 15) << 2;
        int cg = c0 + ci, grp = cg >> 4;
        int bg = b * NGRP + grp;
        float s  = partial[bg * 4]     + partial[bg * 4 + 2];
        float ss = partial[bg * 4 + 1] + partial[bg * 4 + 3];
        float mean = s * GSZI;
        float var  = ss * GSZI - mean * mean;
        float rstd = rsqrtf(var + EPSV);
        float ga = gamma[cg] * rstd, be = beta[cg] - mean * ga;
        float4 v = *(const float4*)&x[((size_t)b * C_DIM + cg) * N_DIM + n0 + n4];
        float vals[4] = {v.x, v.y, v.z, v.w};
        #pragma unroll
        for (int j = 0; j < 4; ++j) {
            int nl = n4 + j;
            *(unsigned short*)(smem + nl * 128 + ((ci * 2) ^ ((nl & 7) << 4))) =
                f2bf(vals[j] * ga + be);
        }
    }
    __syncthreads();
    #pragma unroll
    for (int i = 0; i < 2; ++i) {
        int idx = tid + i * 256;       // 512 chunks = 64 rows x 8x16B
        int row = idx >> 3, ch = idx & 7;
        bf16x8 v = *(const bf16x8*)(smem + row * 128 + ((ch * 16) ^ ((row & 7) << 4)));
        *(bf16x8*)&ht[((size_t)(b * N_DIM + n0 + row)) * C_DIM + c0 + ch * 8] = v;
    }
}

// ---------------------------------------------------------------------------
// cast4: fp32 -> bf16 for the four 512x512 weights in one launch.
// ---------------------------------------------------------------------------
__global__ __launch_bounds__(256) void cast4_bf16(const float* __restrict__ s0,
                                                  const float* __restrict__ s1,
                                                  const float* __restrict__ s2,
                                                  const float* __restrict__ s3,
                                                  unsigned short* __restrict__ dst) {
    int which = blockIdx.y;
    const float* src = (which == 0) ? s0 : (which == 1) ? s1 : (which == 2) ? s2 : s3;
    size_t idx = (size_t)blockIdx.x * 256 + threadIdx.x;
    const float4* s4 = (const float4*)src;
    float4 a = s4[idx * 2], b = s4[idx * 2 + 1];
    bf16x8 o;
    o[0] = (short)f2bf(a.x); o[1] = (short)f2bf(a.y);
    o[2] = (short)f2bf(a.z); o[3] = (short)f2bf(a.w);
    o[4] = (short)f2bf(b.x); o[5] = (short)f2bf(b.y);
    o[6] = (short)f2bf(b.z); o[7] = (short)f2bf(b.w);
    *(bf16x8*)&dst[(size_t)which * 262144 + idx * 8] = o;
}

// ---------------------------------------------------------------------------
// conv_qkv v2: fused Q/K/V convs. (Unchanged.)
// ---------------------------------------------------------------------------
__global__ __launch_bounds__(512) void conv_qkv(const unsigned short* __restrict__ Wall,
                                                const float* __restrict__ q_b,
                                                const float* __restrict__ k_b,
                                                const float* __restrict__ v_b,
                                                const unsigned short* __restrict__ ht,
                                                unsigned short* __restrict__ qt,
                                                unsigned short* __restrict__ kt,
                                                unsigned short* __restrict__ vt,
                                                float escale) {
    __shared__ char smem[40960];     // Bs 16KB | As_q 8KB | As_k 8KB | As_v 8KB

    int bn0 = blockIdx.x * 128;      // flattened b*N + n
    int bo  = blockIdx.y * 64;
    int tid = threadIdx.x;
    int L = tid & 63, w = tid >> 6;
    int g = L >> 4, c = L & 15;
    int wr = w >> 2, wc = w & 3;

    f32x4 acc[3][2][2];
    #pragma unroll
    for (int w3 = 0; w3 < 3; ++w3)
        #pragma unroll
        for (int t = 0; t < 2; ++t)
            #pragma unroll
            for (int u = 0; u < 2; ++u) acc[w3][t][u] = f32x4{0.f, 0.f, 0.f, 0.f};

    for (int k0 = 0; k0 < C_DIM; k0 += 64) {
        if (w < 4) {
            #pragma unroll
            for (int i = 0; i < 4; ++i) {
                int j = w * 4 + i;
                int row = j * 8 + (L >> 3);
                int sl = (L & 7) ^ (row & 7);
                GLL16(ht + (size_t)(bn0 + row) * C_DIM + k0 + sl * 8, smem + j * 1024);
            }
        } else {
            #pragma unroll
            for (int i = 0; i < 6; ++i) {
                int j = (w - 4) * 6 + i;
                int w3 = j >> 3, jj = j & 7;
                int row = jj * 8 + (L >> 3);
                int sl = (L & 7) ^ (row & 7);
                GLL16(Wall + (size_t)w3 * 262144 + (size_t)(bo + row) * C_DIM + k0 + sl * 8,
                      smem + 16384 + j * 1024);
            }
        }
        __syncthreads();

        bf16x8 bfr[2][2];
        #pragma unroll
        for (int u = 0; u < 2; ++u) {
            int row = wc * 32 + u * 16 + c;
            #pragma unroll
            for (int ks = 0; ks < 2; ++ks)
                bfr[u][ks] = *(const bf16x8*)(smem + row * 128 +
                                              ((g * 16 + ks * 64) ^ ((row & 7) << 4)));
        }
        #pragma unroll
        for (int w3 = 0; w3 < 3; ++w3) {
            char* As = smem + 16384 + w3 * 8192;
            bf16x8 af[2][2];
            #pragma unroll
            for (int t = 0; t < 2; ++t) {
                int row = wr * 32 + t * 16 + c;
                #pragma unroll
                for (int ks = 0; ks < 2; ++ks)
                    af[t][ks] = *(const bf16x8*)(As + row * 128 +
                                                 ((g * 16 + ks * 64) ^ ((row & 7) << 4)));
            }
            #pragma unroll
            for (int ks = 0; ks < 2; ++ks)
                #pragma unroll
                for (int t = 0; t < 2; ++t)
                    #pragma unroll
                    for (int u = 0; u < 2; ++u)
                        acc[w3][t][u] = __builtin_amdgcn_mfma_f32_16x16x32_bf16(
                            af[t][ks], bfr[u][ks], acc[w3][t][u], 0, 0, 0);
        }
        __syncthreads();
    }

    int b  = bn0 >> 11;              // N_DIM = 2048
    int nb = bn0 & (N_DIM - 1);
    int hh = bo >> 6;
    int bh = b * NHEAD + hh;

    #pragma unroll
    for (int t = 0; t < 2; ++t)
        #pragma unroll
        for (int r = 0; r < 4; ++r) {
            int m = bo + wr * 32 + t * 16 + g * 4 + r;
            float bi = v_b[m];
            #pragma unroll
            for (int u = 0; u < 2; ++u) {
                int n = nb + wc * 32 + u * 16 + c;
                vt[((size_t)b * C_DIM + m) * N_DIM + n] = f2bf(acc[2][t][u][r] + bi);
            }
        }

    char* Ts = smem;                 // [128 n][64 d] swz
    #pragma unroll
    for (int pass = 0; pass < 2; ++pass) {
        const float* bias = pass ? k_b : q_b;
        float esc = pass ? 1.0f : escale;
        unsigned short* dst = pass ? kt : qt;
        __syncthreads();
        #pragma unroll
        for (int t = 0; t < 2; ++t)
            #pragma unroll
            for (int r = 0; r < 4; ++r) {
                int ml = wr * 32 + t * 16 + g * 4 + r;   // d
                float bi = bias[bo + ml];
                #pragma unroll
                for (int u = 0; u < 2; ++u) {
                    int nl = wc * 32 + u * 16 + c;       // 0..127
                    *(unsigned short*)(Ts + nl * 128 + ((ml * 2) ^ ((nl & 7) << 4))) =
                        f2bf((acc[pass][t][u][r] + bi) * esc);
                }
            }
        __syncthreads();
        #pragma unroll
        for (int i = 0; i < 2; ++i) {
            int idx = tid + i * 512;     // 1024 chunks = 128 rows x 8x16B
            int row = idx >> 3, ch = idx & 7;
            bf16x8 v = *(const bf16x8*)(Ts + row * 128 + ((ch * 16) ^ ((row & 7) << 4)));
            *(bf16x8*)&dst[((size_t)bh * N_DIM + nb + row) * HDIM + ch * 8] = v;
        }
    }
}

// ---------------------------------------------------------------------------
// conv_proj: out fp32 [b][c][n] + residual. (Unchanged.)
// ---------------------------------------------------------------------------
__global__ __launch_bounds__(256) void conv_proj(const unsigned short* __restrict__ Wb,
                                                 const float* __restrict__ bias,
                                                 const unsigned short* __restrict__ Bsrc,
                                                 const float* __restrict__ res,
                                                 float* __restrict__ outf) {
    __shared__ char smem[24576];
    int bn0 = blockIdx.x * 128;
    int bo  = blockIdx.y * 64;
    int tid = threadIdx.x;
    int L = tid & 63, w = tid >> 6;
    int g = L >> 4, c = L & 15;
    int wr = w >> 1, wc = w & 1;

    f32x4 acc[2][4];
    #pragma unroll
    for (int t = 0; t < 2; ++t)
        #pragma unroll
        for (int u = 0; u < 4; ++u) acc[t][u] = f32x4{0.f, 0.f, 0.f, 0.f};

    for (int k0 = 0; k0 < C_DIM; k0 += 64) {
        #pragma unroll
        for (int i = 0; i < 2; ++i) {
            int j = w * 2 + i;
            int ra = j * 8 + (L >> 3);
            int sl = (L & 7) ^ (ra & 7);
            GLL16(Wb + (size_t)(bo + ra) * C_DIM + k0 + sl * 8, smem + j * 1024);
        }
        #pragma unroll
        for (int i = 0; i < 4; ++i) {
            int j = w * 4 + i;
            int rb = j * 8 + (L >> 3);
            int sl = (L & 7) ^ (rb & 7);
            GLL16(Bsrc + (size_t)(bn0 + rb) * C_DIM + k0 + sl * 8, smem + 8192 + j * 1024);
        }
        __syncthreads();

        bf16x8 af[2][2], bfr[4][2];
        #pragma unroll
        for (int t = 0; t < 2; ++t) {
            int row = wr * 32 + t * 16 + c;
            #pragma unroll
            for (int ks = 0; ks < 2; ++ks)
                af[t][ks] = *(const bf16x8*)(smem + row * 128 +
                                             ((g * 16 + ks * 64) ^ ((row & 7) << 4)));
        }
        #pragma unroll
        for (int u = 0; u < 4; ++u) {
            int row = wc * 64 + u * 16 + c;
            #pragma unroll
            for (int ks = 0; ks < 2; ++ks)
                bfr[u][ks] = *(const bf16x8*)(smem + 8192 + row * 128 +
                                              ((g * 16 + ks * 64) ^ ((row & 7) << 4)));
        }
        #pragma unroll
        for (int ks = 0; ks < 2; ++ks)
            #pragma unroll
            for (int t = 0; t < 2; ++t)
                #pragma unroll
                for (int u = 0; u < 4; ++u)
                    acc[t][u] = __builtin_amdgcn_mfma_f32_16x16x32_bf16(
                        af[t][ks], bfr[u][ks], acc[t][u], 0, 0, 0);
        __syncthreads();
    }

    int b  = bn0 >> 11;
    int nb = bn0 & (N_DIM - 1);
    #pragma unroll
    for (int t = 0; t < 2; ++t)
        #pragma unroll
        for (int r = 0; r < 4; ++r) {
            int m = bo + wr * 32 + t * 16 + g * 4 + r;
            float bi = bias[m];
            #pragma unroll
            for (int u = 0; u < 4; ++u) {
                int n = nb + wc * 64 + u * 16 + c;
                size_t off = ((size_t)b * C_DIM + m) * N_DIM + n;
                outf[off] = acc[t][u][r] + bi + res[off];
            }
        }
}

// ---------------------------------------------------------------------------
// MFMA bf16 flash attention, swapped-operand form.
// R14: 4 waves x 32q each (2 q-subtiles/wave) — K/V fragment LDS reads are
// shared across subtiles, cutting LDS-read traffic per unit of work 1.8x.
// XCD remap + counted-vmcnt pipeline retained.
// ---------------------------------------------------------------------------
__global__ __launch_bounds__(256, 2) void attn_kernel(const unsigned short* __restrict__ Qt,
                                                      const unsigned short* __restrict__ Kt,
                                                      const unsigned short* __restrict__ Vt,
                                                      unsigned short* __restrict__ at) {
    __shared__ char smem[49152];
    // [0,16K): Q staging (128 rows x 128B) -> P/O strips; [16K,32K): buf0; [32K,48K): buf1

    // ---- XCD-aware remap (grid = 512 linear blocks, XCD = d % 8) ----
    int d = blockIdx.x;                // 0..511 dispatch id
    int xcd = d & 7;
    int slot = d >> 3;                 // 0..63 within XCD
    int bh = xcd + 8 * (slot >> 4);    // heads {xcd, xcd+8, xcd+16, xcd+24}
    int q0 = (slot & 15) * 128;

    int b = bh >> 3, hh = bh & 7;
    int tid = threadIdx.x;
    int L = tid & 63, w = tid >> 6;        // 4 waves
    int g = L >> 4, c = L & 15;

    const unsigned short* Qh = Qt + (size_t)bh * N_DIM * HDIM;
    const unsigned short* Kh = Kt + (size_t)bh * N_DIM * HDIM;
    const unsigned short* Vh = Vt + (size_t)bh * HDIM * N_DIM;

    // ---- prologue: stage Q (16 chunks) + K/V tile 0 into buf0 ----
    int ssl = (L & 7) ^ (L >> 3);          // swizzled 16B slot (row&7 == L>>3)
    #pragma unroll
    for (int i = 0; i < 4; ++i) {
        int j = w * 4 + i;
        int row = j * 8 + (L >> 3);        // 0..127
        GLL16(Qh + (size_t)(q0 + row) * HDIM + ssl * 8, smem + j * 1024);
    }
    int srow = w * 16 + (L >> 3);          // K/V staging rows (chunks 2w, 2w+1)
    GLL16(Kh + (size_t)srow * HDIM + ssl * 8,        smem + 16384 + (2 * w) * 1024);
    GLL16(Kh + (size_t)(srow + 8) * HDIM + ssl * 8,  smem + 16384 + (2 * w + 1) * 1024);
    GLL16(Vh + (size_t)srow * N_DIM + ssl * 8,       smem + 24576 + (2 * w) * 1024);
    GLL16(Vh + (size_t)(srow + 8) * N_DIM + ssl * 8, smem + 24576 + (2 * w + 1) * 1024);
    __syncthreads();                       // full drain: Q + tile0 ready

    // ---- hoisted addresses ----
    int csw = (c & 7) << 4;
    char* kb0 = smem + 16384 + c * 128 + ((g * 16) ^ csw);        // K frag ks=0
    char* kb1 = smem + 16384 + c * 128 + ((g * 16 + 64) ^ csw);   // K frag ks=1
    char* pb  = smem + (w * 32 + c) * 128;     // subtile-0 strip; subtile-1 = +2048
    int pwo0 = (g * 8) ^ csw;
    int pwo1 = (32 + g * 8) ^ csw;
    int pwo2 = (64 + g * 8) ^ csw;
    int pwo3 = (96 + g * 8) ^ csw;
    int pro0 = (g * 16) ^ csw;
    int pro1 = (64 + g * 16) ^ csw;

    // Q fragments (2 subtiles x 2 ks) from strip region
    bf16x8 qf[2][2];
    #pragma unroll
    for (int s = 0; s < 2; ++s) {
        qf[s][0] = *(const bf16x8*)(pb + s * 2048 + pro0);
        qf[s][1] = *(const bf16x8*)(pb + s * 2048 + pro1);
    }

    // staging global pointers -> tile 1
    const unsigned short* kgp = Kh + (size_t)(64 + srow) * HDIM + ssl * 8;
    const unsigned short* vgp = Vh + (size_t)srow * N_DIM + 64 + ssl * 8;

    f32x4 oacc[2][4];
    #pragma unroll
    for (int s = 0; s < 2; ++s)
        #pragma unroll
        for (int t = 0; t < 4; ++t) oacc[s][t] = f32x4{0.f, 0.f, 0.f, 0.f};
    float m_r[2] = {-INFINITY, -INFINITY};
    float l_part[2] = {0.f, 0.f};

    auto tile = [&](int BOFF) {
        // ---- S^T = K Q^T for both q-subtiles; kf reads SHARED ----
        f32x4 sacc[2][4];
        #pragma unroll
        for (int s = 0; s < 2; ++s)
            #pragma unroll
            for (int t = 0; t < 4; ++t) sacc[s][t] = f32x4{0.f, 0.f, 0.f, 0.f};
        __builtin_amdgcn_s_setprio(1);
        #pragma unroll
        for (int t = 0; t < 4; ++t) {
            bf16x8 kf0 = *(const bf16x8*)(kb0 + BOFF + t * 2048);
            bf16x8 kf1 = *(const bf16x8*)(kb1 + BOFF + t * 2048);
            sacc[0][t] = __builtin_amdgcn_mfma_f32_16x16x32_bf16(kf0, qf[0][0], sacc[0][t], 0, 0, 0);
            sacc[0][t] = __builtin_amdgcn_mfma_f32_16x16x32_bf16(kf1, qf[0][1], sacc[0][t], 0, 0, 0);
            sacc[1][t] = __builtin_amdgcn_mfma_f32_16x16x32_bf16(kf0, qf[1][0], sacc[1][t], 0, 0, 0);
            sacc[1][t] = __builtin_amdgcn_mfma_f32_16x16x32_bf16(kf1, qf[1][1], sacc[1][t], 0, 0, 0);
        }
        __builtin_amdgcn_s_setprio(0);

        // ---- softmax per subtile (exp2 domain); zero-shfl steady state ----
        float mloc[2];
        #pragma unroll
        for (int s = 0; s < 2; ++s) {
            float t0 = fmaxf(fmaxf(sacc[s][0][0], sacc[s][0][1]), sacc[s][0][2]);
            float t1 = fmaxf(fmaxf(sacc[s][0][3], sacc[s][1][0]), sacc[s][1][1]);
            float t2 = fmaxf(fmaxf(sacc[s][1][2], sacc[s][1][3]), sacc[s][2][0]);
            float t3 = fmaxf(fmaxf(sacc[s][2][1], sacc[s][2][2]), sacc[s][2][3]);
            float t4 = fmaxf(fmaxf(sacc[s][3][0], sacc[s][3][1]), sacc[s][3][2]);
            mloc[s] = fmaxf(fmaxf(fmaxf(t0, t1), fmaxf(t2, t3)), fmaxf(t4, sacc[s][3][3]));
        }
        float growth = fmaxf(mloc[0] - m_r[0], mloc[1] - m_r[1]);
        if (!__all(growth <= 6.0f)) {       // rare: row max grew
            #pragma unroll
            for (int s = 0; s < 2; ++s) {
                float ms = mloc[s];
                ms = fmaxf(ms, __shfl_xor(ms, 16));
                ms = fmaxf(ms, __shfl_xor(ms, 32));
                float mn = fmaxf(m_r[s], ms);
                float fac = exp2f(m_r[s] - mn);
                m_r[s] = mn;
                l_part[s] *= fac;
                #pragma unroll
                for (int t = 0; t < 4; ++t) oacc[s][t] = oacc[s][t] * fac;
            }
        }
        unsigned pk[2][4][2];
        #pragma unroll
        for (int s = 0; s < 2; ++s) {
            f32x4 m4 = {m_r[s], m_r[s], m_r[s], m_r[s]};
            f32x4 p[4];
            #pragma unroll
            for (int t = 0; t < 4; ++t) {
                f32x4 dd = sacc[s][t] - m4;
                p[t][0] = exp2f(dd[0]);
                p[t][1] = exp2f(dd[1]);
                p[t][2] = exp2f(dd[2]);
                p[t][3] = exp2f(dd[3]);
            }
            f32x4 racc = (p[0] + p[1]) + (p[2] + p[3]);
            l_part[s] += (racc[0] + racc[1]) + (racc[2] + racc[3]);
            #pragma unroll
            for (int t = 0; t < 4; ++t) {
                pk[s][t][0] = BFPACK(p[t][0], p[t][1]);
                pk[s][t][1] = BFPACK(p[t][2], p[t][3]);
            }
        }

        // ---- P^T strips (wave-private) ----
        #pragma unroll
        for (int s = 0; s < 2; ++s) {
            char* sb = pb + s * 2048;
            *(unsigned long long*)(sb + pwo0) = (unsigned long long)pk[s][0][0] | ((unsigned long long)pk[s][0][1] << 32);
            *(unsigned long long*)(sb + pwo1) = (unsigned long long)pk[s][1][0] | ((unsigned long long)pk[s][1][1] << 32);
            *(unsigned long long*)(sb + pwo2) = (unsigned long long)pk[s][2][0] | ((unsigned long long)pk[s][2][1] << 32);
            *(unsigned long long*)(sb + pwo3) = (unsigned long long)pk[s][3][0] | ((unsigned long long)pk[s][3][1] << 32);
        }

        // ---- O^T += V^T P^T for both subtiles; vf reads SHARED ----
        __builtin_amdgcn_s_setprio(1);
        #pragma unroll
        for (int ks = 0; ks < 2; ++ks) {
            char* kbase = (ks == 0 ? kb0 : kb1) + BOFF + 8192;
            bf16x8 pf0 = *(const bf16x8*)(pb + (ks ? pro1 : pro0));
            bf16x8 pf1 = *(const bf16x8*)(pb + 2048 + (ks ? pro1 : pro0));
            #pragma unroll
            for (int t = 0; t < 4; ++t) {
                bf16x8 vf = *(const bf16x8*)(kbase + t * 2048);
                oacc[0][t] = __builtin_amdgcn_mfma_f32_16x16x32_bf16(vf, pf0, oacc[0][t], 0, 0, 0);
                oacc[1][t] = __builtin_amdgcn_mfma_f32_16x16x32_bf16(vf, pf1, oacc[1][t], 0, 0, 0);
            }
        }
        __builtin_amdgcn_s_setprio(0);
    };

    // T4 pipeline helpers
    #define ATTN_BARRIER() do { \
        __builtin_amdgcn_s_barrier(); \
        asm volatile("" ::: "memory"); \
    } while (0)
    #define ATTN_VMCNT4() do { \
        asm volatile("s_waitcnt vmcnt(4)" ::: "memory"); \
        __builtin_amdgcn_sched_barrier(0); \
    } while (0)
    #define ATTN_VMCNT0() do { \
        asm volatile("s_waitcnt vmcnt(0)" ::: "memory"); \
        __builtin_amdgcn_sched_barrier(0); \
    } while (0)

    for (int i = 0; i < 15; ++i) {
        // tile 2i (buf0); stage tile 2i+1 -> buf1
        ATTN_BARRIER();
        GLL16(kgp,              smem + 32768 + (2 * w) * 1024);
        GLL16(kgp + 8 * HDIM,   smem + 32768 + (2 * w + 1) * 1024);
        GLL16(vgp,              smem + 40960 + (2 * w) * 1024);
        GLL16(vgp + 8 * N_DIM,  smem + 40960 + (2 * w + 1) * 1024);
        kgp += 64 * HDIM;
        vgp += 64;
        ATTN_VMCNT4();
        tile(0);
        // tile 2i+1 (buf1); stage tile 2i+2 -> buf0
        ATTN_BARRIER();
        GLL16(kgp,              smem + 16384 + (2 * w) * 1024);
        GLL16(kgp + 8 * HDIM,   smem + 16384 + (2 * w + 1) * 1024);
        GLL16(vgp,              smem + 24576 + (2 * w) * 1024);
        GLL16(vgp + 8 * N_DIM,  smem + 24576 + (2 * w + 1) * 1024);
        kgp += 64 * HDIM;
        vgp += 64;
        ATTN_VMCNT4();
        tile(16384);
    }
    // tile 30 (buf0); stage tile 31 -> buf1
    ATTN_BARRIER();
    GLL16(kgp,              smem + 32768 + (2 * w) * 1024);
    GLL16(kgp + 8 * HDIM,   smem + 32768 + (2 * w + 1) * 1024);
    GLL16(vgp,              smem + 40960 + (2 * w) * 1024);
    GLL16(vgp + 8 * N_DIM,  smem + 40960 + (2 * w + 1) * 1024);
    ATTN_VMCNT4();
    tile(0);
    // tile 31 (buf1); no more staging -> full drain
    ATTN_BARRIER();
    ATTN_VMCNT0();
    tile(16384);

    #undef ATTN_BARRIER
    #undef ATTN_VMCNT4
    #undef ATTN_VMCNT0

    // ---- deferred l reduction + epilogue (wave-private strips) ----
    #pragma unroll
    for (int s = 0; s < 2; ++s) {
        float l_r = l_part[s];
        l_r += __shfl_xor(l_r, 16);
        l_r += __shfl_xor(l_r, 32);
        float oinv = 1.f / l_r;
        char* sb = pb + s * 2048;
        unsigned lo, hi;
        lo = BFPACK(oacc[s][0][0] * oinv, oacc[s][0][1] * oinv);
        hi = BFPACK(oacc[s][0][2] * oinv, oacc[s][0][3] * oinv);
        *(unsigned long long*)(sb + pwo0) = (unsigned long long)lo | ((unsigned long long)hi << 32);
        lo = BFPACK(oacc[s][1][0] * oinv, oacc[s][1][1] * oinv);
        hi = BFPACK(oacc[s][1][2] * oinv, oacc[s][1][3] * oinv);
        *(unsigned long long*)(sb + pwo1) = (unsigned long long)lo | ((unsigned long long)hi << 32);
        lo = BFPACK(oacc[s][2][0] * oinv, oacc[s][2][1] * oinv);
        hi = BFPACK(oacc[s][2][2] * oinv, oacc[s][2][3] * oinv);
        *(unsigned long long*)(sb + pwo2) = (unsigned long long)lo | ((unsigned long long)hi << 32);
        lo = BFPACK(oacc[s][3][0] * oinv, oacc[s][3][1] * oinv);
        hi = BFPACK(oacc[s][3][2] * oinv, oacc[s][3][3] * oinv);
        *(unsigned long long*)(sb + pwo3) = (unsigned long long)lo | ((unsigned long long)hi << 32);
    }
    char* wbase = smem + w * 4096;         // wave's 32 rows
    #pragma unroll
    for (int i = 0; i < 4; ++i) {
        int idx = L + i * 64;              // 256 chunks = 32 rows x 8x16B
        int row = idx >> 3, ch = idx & 7;
        bf16x8 v = *(const bf16x8*)(wbase + row * 128 + ((ch * 16) ^ ((row & 7) << 4)));
        *(bf16x8*)&at[((size_t)(b * N_DIM + q0 + w * 32 + row)) * C_DIM + hh * HDIM + ch * 8] = v;
    }
}

// ---------------------------------------------------------------------------
extern "C" void kernel_launch(void* const* d_in, const int* in_sizes, int n_in,
                              void* d_out, int out_size, void* d_ws, size_t ws_size,
                              hipStream_t stream) {
    (void)in_sizes; (void)n_in; (void)out_size; (void)ws_size;
    const float* x     = (const float*)d_in[0];
    const float* gam   = (const float*)d_in[1];
    const float* bet   = (const float*)d_in[2];
    const float* q_w   = (const float*)d_in[3];
    const float* q_b   = (const float*)d_in[4];
    const float* k_w   = (const float*)d_in[5];
    const float* k_b   = (const float*)d_in[6];
    const float* v_w   = (const float*)d_in[7];
    const float* v_b   = (const float*)d_in[8];
    const float* p_w   = (const float*)d_in[9];
    const float* p_b   = (const float*)d_in[10];
    float* out = (float*)d_out;

    const size_t MB = 1 << 20;
    char* wsb = (char*)d_ws;
    unsigned short* ht  = (unsigned short*)(wsb);              // 8 MB  [8192][512]
    unsigned short* wqb = (unsigned short*)(wsb + 8 * MB);     // 4 x 512KB contiguous (q,k,v,p)
    unsigned short* wpb = (unsigned short*)(wsb + 9 * MB + 512 * 1024);
    float*          partial = (float*)(wsb + 10 * MB);         // 2 KB
    unsigned short* qt  = (unsigned short*)(wsb + 11 * MB);    // 8 MB [bh][n][d]
    unsigned short* kt  = (unsigned short*)(wsb + 19 * MB);    // 8 MB
    unsigned short* vt  = (unsigned short*)(wsb + 27 * MB);    // 8 MB [b][c][n]
    unsigned short* at  = (unsigned short*)(wsb + 35 * MB);    // 8 MB [b][n][c]

    gn_stats<<<B_DIM * NGRP * 2, 256, 0, stream>>>(x, partial);
    gn_apply_t<<<dim3(N_DIM / 64, C_DIM / 64, B_DIM), 256, 0, stream>>>(x, partial, gam, bet, ht);

    cast4_bf16<<<dim3(128, 4), 256, 0, stream>>>(q_w, k_w, v_w, p_w, wqb);

    const float escale = 0.044194173824159216f * 1.4426950408889634f;  // scale*log2(e)
    conv_qkv<<<dim3(B_DIM * N_DIM / 128, C_DIM / 64), 512, 0, stream>>>(
        wqb, q_b, k_b, v_b, ht, qt, kt, vt, escale);

    attn_kernel<<<512, 256, 0, stream>>>(qt, kt, vt, at);

    conv_proj<<<dim3(B_DIM * N_DIM / 128, C_DIM / 64), 256, 0, stream>>>(wpb, p_b, at, x, out);
}

// Round 15
// 116.368 us; speedup vs baseline: 1.0414x; 1.0414x over previous
//
#include <hip/hip_runtime.h>
#include <hip/hip_bf16.h>
#include <math.h>

#define C_DIM 512
#define N_DIM 2048
#define B_DIM 4
#define NGRP 32
#define GCH 16          // channels per group
#define NHEAD 8
#define HDIM 64
#define EPSV 1e-6f

using f32x4  = __attribute__((ext_vector_type(4))) float;
using f32x16 = __attribute__((ext_vector_type(16))) float;
using bf16x8 = __attribute__((ext_vector_type(8))) short;   // 8 bf16 raw bits (4 VGPRs)

// async global->LDS, 16B per lane; LDS dest = wave-uniform base + lane*16
#define GLL16(gp, lp) __builtin_amdgcn_global_load_lds( \
    (const __attribute__((address_space(1))) unsigned int*)(gp), \
    (__attribute__((address_space(3))) unsigned int*)(lp), 16, 0, 0)

// pack high-16 (truncated bf16) of two f32s: lo16 = a, hi16 = b
#define BFPACK(a, b) __builtin_amdgcn_perm(__float_as_uint(b), __float_as_uint(a), 0x07060302u)

static __device__ __forceinline__ unsigned short f2bf(float f) {
    union { __hip_bfloat16 h; unsigned short u; } cv;
    cv.h = __float2bfloat16(f);
    return cv.u;
}

static __device__ __forceinline__ f32x16 zero16() {
    f32x16 z;
    #pragma unroll
    for (int i = 0; i < 16; ++i) z[i] = 0.f;
    return z;
}

static __device__ __forceinline__ bf16x8 mk8(unsigned u0, unsigned u1, unsigned u2, unsigned u3) {
    union { unsigned u[4]; bf16x8 v; } x;
    x.u[0] = u0; x.u[1] = u1; x.u[2] = u2; x.u[3] = u3;
    return x.v;
}

// ---------------------------------------------------------------------------
// gn_stats: 2 blocks per (b,group) half-slab; partial sums.
// ---------------------------------------------------------------------------
__global__ __launch_bounds__(256) void gn_stats(const float* __restrict__ x,
                                                float* __restrict__ partial) {
    const int HSZ = GCH * N_DIM / 2;        // 16384 floats per half
    int blk = blockIdx.x;                   // 0..255
    const float4* x4 = (const float4*)(x + (size_t)blk * HSZ);
    int tid = threadIdx.x;

    float s = 0.f, ss = 0.f;
    #pragma unroll
    for (int it = 0; it < HSZ / 4 / 256; ++it) {
        float4 v = x4[tid + it * 256];
        s  += v.x + v.y + v.z + v.w;
        ss += v.x * v.x + v.y * v.y + v.z * v.z + v.w * v.w;
    }
    __shared__ float rs[256], rss[256];
    rs[tid] = s; rss[tid] = ss;
    __syncthreads();
    for (int off = 128; off > 0; off >>= 1) {
        if (tid < off) { rs[tid] += rs[tid + off]; rss[tid] += rss[tid + off]; }
        __syncthreads();
    }
    if (tid == 0) {
        partial[blk * 2]     = rs[0];
        partial[blk * 2 + 1] = rss[0];
    }
}

// ---------------------------------------------------------------------------
// gn_apply_t: x [b][c][n] fp32 -> ht [(b*n)][c] bf16 (normalized, transposed).
// ---------------------------------------------------------------------------
__global__ __launch_bounds__(256) void gn_apply_t(const float* __restrict__ x,
                                                  const float* __restrict__ partial,
                                                  const float* __restrict__ gamma,
                                                  const float* __restrict__ beta,
                                                  unsigned short* __restrict__ ht) {
    __shared__ char smem[8192];     // [64 n][64 c] bf16, rows 128B, XOR-swizzled
    const float GSZI = 1.f / (GCH * N_DIM);
    int n0 = blockIdx.x * 64, c0 = blockIdx.y * 64, b = blockIdx.z;
    int tid = threadIdx.x;
    #pragma unroll
    for (int it = 0; it < 4; ++it) {
        int idx = tid + it * 256;
        int ci = idx >> 4, n4 = (idx & 15) << 2;
        int cg = c0 + ci, grp = cg >> 4;
        int bg = b * NGRP + grp;
        float s  = partial[bg * 4]     + partial[bg * 4 + 2];
        float ss = partial[bg * 4 + 1] + partial[bg * 4 + 3];
        float mean = s * GSZI;
        float var  = ss * GSZI - mean * mean;
        float rstd = rsqrtf(var + EPSV);
        float ga = gamma[cg] * rstd, be = beta[cg] - mean * ga;
        float4 v = *(const float4*)&x[((size_t)b * C_DIM + cg) * N_DIM + n0 + n4];
        float vals[4] = {v.x, v.y, v.z, v.w};
        #pragma unroll
        for (int j = 0; j < 4; ++j) {
            int nl = n4 + j;
            *(unsigned short*)(smem + nl * 128 + ((ci * 2) ^ ((nl & 7) << 4))) =
                f2bf(vals[j] * ga + be);
        }
    }
    __syncthreads();
    #pragma unroll
    for (int i = 0; i < 2; ++i) {
        int idx = tid + i * 256;       // 512 chunks = 64 rows x 8x16B
        int row = idx >> 3, ch = idx & 7;
        bf16x8 v = *(const bf16x8*)(smem + row * 128 + ((ch * 16) ^ ((row & 7) << 4)));
        *(bf16x8*)&ht[((size_t)(b * N_DIM + n0 + row)) * C_DIM + c0 + ch * 8] = v;
    }
}

// ---------------------------------------------------------------------------
// cast4: fp32 -> bf16 for the four 512x512 weights in one launch.
// ---------------------------------------------------------------------------
__global__ __launch_bounds__(256) void cast4_bf16(const float* __restrict__ s0,
                                                  const float* __restrict__ s1,
                                                  const float* __restrict__ s2,
                                                  const float* __restrict__ s3,
                                                  unsigned short* __restrict__ dst) {
    int which = blockIdx.y;
    const float* src = (which == 0) ? s0 : (which == 1) ? s1 : (which == 2) ? s2 : s3;
    size_t idx = (size_t)blockIdx.x * 256 + threadIdx.x;
    const float4* s4 = (const float4*)src;
    float4 a = s4[idx * 2], b = s4[idx * 2 + 1];
    bf16x8 o;
    o[0] = (short)f2bf(a.x); o[1] = (short)f2bf(a.y);
    o[2] = (short)f2bf(a.z); o[3] = (short)f2bf(a.w);
    o[4] = (short)f2bf(b.x); o[5] = (short)f2bf(b.y);
    o[6] = (short)f2bf(b.z); o[7] = (short)f2bf(b.w);
    *(bf16x8*)&dst[(size_t)which * 262144 + idx * 8] = o;
}

// ---------------------------------------------------------------------------
// conv_qkv v2: fused Q/K/V convs. (Unchanged.)
// ---------------------------------------------------------------------------
__global__ __launch_bounds__(512) void conv_qkv(const unsigned short* __restrict__ Wall,
                                                const float* __restrict__ q_b,
                                                const float* __restrict__ k_b,
                                                const float* __restrict__ v_b,
                                                const unsigned short* __restrict__ ht,
                                                unsigned short* __restrict__ qt,
                                                unsigned short* __restrict__ kt,
                                                unsigned short* __restrict__ vt,
                                                float escale) {
    __shared__ char smem[40960];     // Bs 16KB | As_q 8KB | As_k 8KB | As_v 8KB

    int bn0 = blockIdx.x * 128;      // flattened b*N + n
    int bo  = blockIdx.y * 64;
    int tid = threadIdx.x;
    int L = tid & 63, w = tid >> 6;
    int g = L >> 4, c = L & 15;
    int wr = w >> 2, wc = w & 3;

    f32x4 acc[3][2][2];
    #pragma unroll
    for (int w3 = 0; w3 < 3; ++w3)
        #pragma unroll
        for (int t = 0; t < 2; ++t)
            #pragma unroll
            for (int u = 0; u < 2; ++u) acc[w3][t][u] = f32x4{0.f, 0.f, 0.f, 0.f};

    for (int k0 = 0; k0 < C_DIM; k0 += 64) {
        if (w < 4) {
            #pragma unroll
            for (int i = 0; i < 4; ++i) {
                int j = w * 4 + i;
                int row = j * 8 + (L >> 3);
                int sl = (L & 7) ^ (row & 7);
                GLL16(ht + (size_t)(bn0 + row) * C_DIM + k0 + sl * 8, smem + j * 1024);
            }
        } else {
            #pragma unroll
            for (int i = 0; i < 6; ++i) {
                int j = (w - 4) * 6 + i;
                int w3 = j >> 3, jj = j & 7;
                int row = jj * 8 + (L >> 3);
                int sl = (L & 7) ^ (row & 7);
                GLL16(Wall + (size_t)w3 * 262144 + (size_t)(bo + row) * C_DIM + k0 + sl * 8,
                      smem + 16384 + j * 1024);
            }
        }
        __syncthreads();

        bf16x8 bfr[2][2];
        #pragma unroll
        for (int u = 0; u < 2; ++u) {
            int row = wc * 32 + u * 16 + c;
            #pragma unroll
            for (int ks = 0; ks < 2; ++ks)
                bfr[u][ks] = *(const bf16x8*)(smem + row * 128 +
                                              ((g * 16 + ks * 64) ^ ((row & 7) << 4)));
        }
        #pragma unroll
        for (int w3 = 0; w3 < 3; ++w3) {
            char* As = smem + 16384 + w3 * 8192;
            bf16x8 af[2][2];
            #pragma unroll
            for (int t = 0; t < 2; ++t) {
                int row = wr * 32 + t * 16 + c;
                #pragma unroll
                for (int ks = 0; ks < 2; ++ks)
                    af[t][ks] = *(const bf16x8*)(As + row * 128 +
                                                 ((g * 16 + ks * 64) ^ ((row & 7) << 4)));
            }
            #pragma unroll
            for (int ks = 0; ks < 2; ++ks)
                #pragma unroll
                for (int t = 0; t < 2; ++t)
                    #pragma unroll
                    for (int u = 0; u < 2; ++u)
                        acc[w3][t][u] = __builtin_amdgcn_mfma_f32_16x16x32_bf16(
                            af[t][ks], bfr[u][ks], acc[w3][t][u], 0, 0, 0);
        }
        __syncthreads();
    }

    int b  = bn0 >> 11;              // N_DIM = 2048
    int nb = bn0 & (N_DIM - 1);
    int hh = bo >> 6;
    int bh = b * NHEAD + hh;

    #pragma unroll
    for (int t = 0; t < 2; ++t)
        #pragma unroll
        for (int r = 0; r < 4; ++r) {
            int m = bo + wr * 32 + t * 16 + g * 4 + r;
            float bi = v_b[m];
            #pragma unroll
            for (int u = 0; u < 2; ++u) {
                int n = nb + wc * 32 + u * 16 + c;
                vt[((size_t)b * C_DIM + m) * N_DIM + n] = f2bf(acc[2][t][u][r] + bi);
            }
        }

    char* Ts = smem;                 // [128 n][64 d] swz
    #pragma unroll
    for (int pass = 0; pass < 2; ++pass) {
        const float* bias = pass ? k_b : q_b;
        float esc = pass ? 1.0f : escale;
        unsigned short* dst = pass ? kt : qt;
        __syncthreads();
        #pragma unroll
        for (int t = 0; t < 2; ++t)
            #pragma unroll
            for (int r = 0; r < 4; ++r) {
                int ml = wr * 32 + t * 16 + g * 4 + r;   // d
                float bi = bias[bo + ml];
                #pragma unroll
                for (int u = 0; u < 2; ++u) {
                    int nl = wc * 32 + u * 16 + c;       // 0..127
                    *(unsigned short*)(Ts + nl * 128 + ((ml * 2) ^ ((nl & 7) << 4))) =
                        f2bf((acc[pass][t][u][r] + bi) * esc);
                }
            }
        __syncthreads();
        #pragma unroll
        for (int i = 0; i < 2; ++i) {
            int idx = tid + i * 512;     // 1024 chunks = 128 rows x 8x16B
            int row = idx >> 3, ch = idx & 7;
            bf16x8 v = *(const bf16x8*)(Ts + row * 128 + ((ch * 16) ^ ((row & 7) << 4)));
            *(bf16x8*)&dst[((size_t)bh * N_DIM + nb + row) * HDIM + ch * 8] = v;
        }
    }
}

// ---------------------------------------------------------------------------
// conv_proj: out fp32 [b][c][n] + residual. (Unchanged.)
// ---------------------------------------------------------------------------
__global__ __launch_bounds__(256) void conv_proj(const unsigned short* __restrict__ Wb,
                                                 const float* __restrict__ bias,
                                                 const unsigned short* __restrict__ Bsrc,
                                                 const float* __restrict__ res,
                                                 float* __restrict__ outf) {
    __shared__ char smem[24576];
    int bn0 = blockIdx.x * 128;
    int bo  = blockIdx.y * 64;
    int tid = threadIdx.x;
    int L = tid & 63, w = tid >> 6;
    int g = L >> 4, c = L & 15;
    int wr = w >> 1, wc = w & 1;

    f32x4 acc[2][4];
    #pragma unroll
    for (int t = 0; t < 2; ++t)
        #pragma unroll
        for (int u = 0; u < 4; ++u) acc[t][u] = f32x4{0.f, 0.f, 0.f, 0.f};

    for (int k0 = 0; k0 < C_DIM; k0 += 64) {
        #pragma unroll
        for (int i = 0; i < 2; ++i) {
            int j = w * 2 + i;
            int ra = j * 8 + (L >> 3);
            int sl = (L & 7) ^ (ra & 7);
            GLL16(Wb + (size_t)(bo + ra) * C_DIM + k0 + sl * 8, smem + j * 1024);
        }
        #pragma unroll
        for (int i = 0; i < 4; ++i) {
            int j = w * 4 + i;
            int rb = j * 8 + (L >> 3);
            int sl = (L & 7) ^ (rb & 7);
            GLL16(Bsrc + (size_t)(bn0 + rb) * C_DIM + k0 + sl * 8, smem + 8192 + j * 1024);
        }
        __syncthreads();

        bf16x8 af[2][2], bfr[4][2];
        #pragma unroll
        for (int t = 0; t < 2; ++t) {
            int row = wr * 32 + t * 16 + c;
            #pragma unroll
            for (int ks = 0; ks < 2; ++ks)
                af[t][ks] = *(const bf16x8*)(smem + row * 128 +
                                             ((g * 16 + ks * 64) ^ ((row & 7) << 4)));
        }
        #pragma unroll
        for (int u = 0; u < 4; ++u) {
            int row = wc * 64 + u * 16 + c;
            #pragma unroll
            for (int ks = 0; ks < 2; ++ks)
                bfr[u][ks] = *(const bf16x8*)(smem + 8192 + row * 128 +
                                              ((g * 16 + ks * 64) ^ ((row & 7) << 4)));
        }
        #pragma unroll
        for (int ks = 0; ks < 2; ++ks)
            #pragma unroll
            for (int t = 0; t < 2; ++t)
                #pragma unroll
                for (int u = 0; u < 4; ++u)
                    acc[t][u] = __builtin_amdgcn_mfma_f32_16x16x32_bf16(
                        af[t][ks], bfr[u][ks], acc[t][u], 0, 0, 0);
        __syncthreads();
    }

    int b  = bn0 >> 11;
    int nb = bn0 & (N_DIM - 1);
    #pragma unroll
    for (int t = 0; t < 2; ++t)
        #pragma unroll
        for (int r = 0; r < 4; ++r) {
            int m = bo + wr * 32 + t * 16 + g * 4 + r;
            float bi = bias[m];
            #pragma unroll
            for (int u = 0; u < 4; ++u) {
                int n = nb + wc * 64 + u * 16 + c;
                size_t off = ((size_t)b * C_DIM + m) * N_DIM + n;
                outf[off] = acc[t][u][r] + bi + res[off];
            }
        }
}

// ---------------------------------------------------------------------------
// MFMA bf16 flash attention, 32x32x16 shape, in-register P (permlane32_swap).
// 4 waves x 32q (QBLK=128). Layouts:
//   C/D: col=lane&31, row=(reg&3)+8*(reg>>2)+4*(lane>>5)   [m74/m101]
//   A/B: row|col=lane&31, k=(lane>>5)*8+e
// K/V staged via GLL16 double-buffer + counted vmcnt; XCD remap retained.
// ---------------------------------------------------------------------------
__global__ __launch_bounds__(256, 2) void attn_kernel(const unsigned short* __restrict__ Qt,
                                                      const unsigned short* __restrict__ Kt,
                                                      const unsigned short* __restrict__ Vt,
                                                      unsigned short* __restrict__ at) {
    __shared__ char smem[49152];
    // [0,16K): Q staging (128 rows x 128B) -> O strips; [16K,32K): buf0 (K|V); [32K,48K): buf1

    // ---- XCD-aware remap (512 blocks, XCD = d % 8) ----
    int d = blockIdx.x;
    int xcd = d & 7;
    int slot = d >> 3;                 // 0..63
    int bh = xcd + 8 * (slot >> 4);    // heads {xcd, xcd+8, xcd+16, xcd+24}
    int q0 = (slot & 15) * 128;

    int b = bh >> 3, hh = bh & 7;
    int tid = threadIdx.x;
    int L = tid & 63, w = tid >> 6;        // 4 waves
    int c32 = L & 31, h = L >> 5;

    const unsigned short* Qh = Qt + (size_t)bh * N_DIM * HDIM;
    const unsigned short* Kh = Kt + (size_t)bh * N_DIM * HDIM;
    const unsigned short* Vh = Vt + (size_t)bh * HDIM * N_DIM;

    // ---- prologue: stage Q (16 chunks) + K/V tile 0 into buf0 ----
    int ssl = (L & 7) ^ (L >> 3);          // pre-swizzled 16B slot
    #pragma unroll
    for (int i = 0; i < 4; ++i) {
        int j = w * 4 + i;
        int row = j * 8 + (L >> 3);        // 0..127
        GLL16(Qh + (size_t)(q0 + row) * HDIM + ssl * 8, smem + j * 1024);
    }
    int srow = w * 16 + (L >> 3);          // staging rows (chunks 2w, 2w+1)
    GLL16(Kh + (size_t)srow * HDIM + ssl * 8,        smem + 16384 + (2 * w) * 1024);
    GLL16(Kh + (size_t)(srow + 8) * HDIM + ssl * 8,  smem + 16384 + (2 * w + 1) * 1024);
    GLL16(Vh + (size_t)srow * N_DIM + ssl * 8,       smem + 24576 + (2 * w) * 1024);
    GLL16(Vh + (size_t)(srow + 8) * N_DIM + ssl * 8, smem + 24576 + (2 * w + 1) * 1024);
    __syncthreads();                       // full drain: Q + tile0 ready

    // ---- hoisted addresses ----
    int kswz = (c32 & 7) << 4;
    int ko[4];
    #pragma unroll
    for (int s = 0; s < 4; ++s) ko[s] = (h * 16 + 32 * s) ^ kswz;
    char* rowK = smem + 16384 + c32 * 128;     // + BOFF + kb*4096 (K), +8192+db*4096 (V)
    char* strip = smem + (w * 32 + c32) * 128; // wave's q-row in Q region

    // Q fragments (B-operand): col=q=c32, k(d)=h*8+e+16s
    bf16x8 qf[4];
    #pragma unroll
    for (int s = 0; s < 4; ++s)
        qf[s] = *(const bf16x8*)(strip + ko[s]);

    // staging global pointers -> tile 1
    const unsigned short* kgp = Kh + (size_t)(64 + srow) * HDIM + ssl * 8;
    const unsigned short* vgp = Vh + (size_t)srow * N_DIM + 64 + ssl * 8;

    f32x16 oacc0 = zero16(), oacc1 = zero16();
    float m_r = -INFINITY, l_part = 0.f;

    auto tile = [&](int BOFF) {
        // ---- S^T = K Q^T : D[kpos(kb)][q] ----
        f32x16 sacc0 = zero16(), sacc1 = zero16();
        __builtin_amdgcn_s_setprio(1);
        #pragma unroll
        for (int s = 0; s < 4; ++s) {
            bf16x8 kf0 = *(const bf16x8*)(rowK + BOFF + ko[s]);
            bf16x8 kf1 = *(const bf16x8*)(rowK + BOFF + 4096 + ko[s]);
            sacc0 = __builtin_amdgcn_mfma_f32_32x32x16_bf16(kf0, qf[s], sacc0, 0, 0, 0);
            sacc1 = __builtin_amdgcn_mfma_f32_32x32x16_bf16(kf1, qf[s], sacc1, 0, 0, 0);
        }
        __builtin_amdgcn_s_setprio(0);

        // ---- softmax over kpos (exp2 domain); zero-shfl steady state ----
        float mloc = -INFINITY;
        #pragma unroll
        for (int r = 0; r < 16; ++r) mloc = fmaxf(mloc, fmaxf(sacc0[r], sacc1[r]));
        if (!__all(mloc - m_r <= 6.0f)) {       // rare: row max grew
            mloc = fmaxf(mloc, __shfl_xor(mloc, 32));
            float mn = fmaxf(m_r, mloc);
            float fac = exp2f(m_r - mn);
            m_r = mn;
            l_part *= fac;
            oacc0 = oacc0 * fac;
            oacc1 = oacc1 * fac;
        }
        // exp2 + pack + permlane exchange -> PV B-frags fully in-register
        bf16x8 pf[4];
        float rs = 0.f;
        {
            float p[16];
            #pragma unroll
            for (int r = 0; r < 16; ++r) { p[r] = exp2f(sacc0[r] - m_r); rs += p[r]; }
            unsigned a0 = BFPACK(p[0], p[1]),   bb0 = BFPACK(p[2], p[3]);
            unsigned a1 = BFPACK(p[4], p[5]),   bb1 = BFPACK(p[6], p[7]);
            unsigned a2 = BFPACK(p[8], p[9]),   bb2 = BFPACK(p[10], p[11]);
            unsigned a3 = BFPACK(p[12], p[13]), bb3 = BFPACK(p[14], p[15]);
            asm volatile("v_permlane32_swap_b32 %0, %1" : "+v"(a0), "+v"(a1));
            asm volatile("v_permlane32_swap_b32 %0, %1" : "+v"(bb0), "+v"(bb1));
            asm volatile("v_permlane32_swap_b32 %0, %1" : "+v"(a2), "+v"(a3));
            asm volatile("v_permlane32_swap_b32 %0, %1" : "+v"(bb2), "+v"(bb3));
            pf[0] = mk8(a0, bb0, a1, bb1);
            pf[1] = mk8(a2, bb2, a3, bb3);
        }
        {
            float p[16];
            #pragma unroll
            for (int r = 0; r < 16; ++r) { p[r] = exp2f(sacc1[r] - m_r); rs += p[r]; }
            unsigned a0 = BFPACK(p[0], p[1]),   bb0 = BFPACK(p[2], p[3]);
            unsigned a1 = BFPACK(p[4], p[5]),   bb1 = BFPACK(p[6], p[7]);
            unsigned a2 = BFPACK(p[8], p[9]),   bb2 = BFPACK(p[10], p[11]);
            unsigned a3 = BFPACK(p[12], p[13]), bb3 = BFPACK(p[14], p[15]);
            asm volatile("v_permlane32_swap_b32 %0, %1" : "+v"(a0), "+v"(a1));
            asm volatile("v_permlane32_swap_b32 %0, %1" : "+v"(bb0), "+v"(bb1));
            asm volatile("v_permlane32_swap_b32 %0, %1" : "+v"(a2), "+v"(a3));
            asm volatile("v_permlane32_swap_b32 %0, %1" : "+v"(bb2), "+v"(bb3));
            pf[2] = mk8(a0, bb0, a1, bb1);
            pf[3] = mk8(a2, bb2, a3, bb3);
        }
        l_part += rs;

        // ---- O^T += V^T P^T : A = V rows (d), B = pf slices ----
        __builtin_amdgcn_s_setprio(1);
        #pragma unroll
        for (int s = 0; s < 4; ++s) {
            bf16x8 vf0 = *(const bf16x8*)(rowK + BOFF + 8192 + ko[s]);
            bf16x8 vf1 = *(const bf16x8*)(rowK + BOFF + 8192 + 4096 + ko[s]);
            oacc0 = __builtin_amdgcn_mfma_f32_32x32x16_bf16(vf0, pf[s], oacc0, 0, 0, 0);
            oacc1 = __builtin_amdgcn_mfma_f32_32x32x16_bf16(vf1, pf[s], oacc1, 0, 0, 0);
        }
        __builtin_amdgcn_s_setprio(0);
    };

    #define ATTN_BARRIER() do { \
        __builtin_amdgcn_s_barrier(); \
        asm volatile("" ::: "memory"); \
    } while (0)
    #define ATTN_VMCNT4() do { \
        asm volatile("s_waitcnt vmcnt(4)" ::: "memory"); \
        __builtin_amdgcn_sched_barrier(0); \
    } while (0)
    #define ATTN_VMCNT0() do { \
        asm volatile("s_waitcnt vmcnt(0)" ::: "memory"); \
        __builtin_amdgcn_sched_barrier(0); \
    } while (0)

    for (int i = 0; i < 15; ++i) {
        ATTN_BARRIER();
        GLL16(kgp,              smem + 32768 + (2 * w) * 1024);
        GLL16(kgp + 8 * HDIM,   smem + 32768 + (2 * w + 1) * 1024);
        GLL16(vgp,              smem + 40960 + (2 * w) * 1024);
        GLL16(vgp + 8 * N_DIM,  smem + 40960 + (2 * w + 1) * 1024);
        kgp += 64 * HDIM;
        vgp += 64;
        ATTN_VMCNT4();
        tile(0);
        ATTN_BARRIER();
        GLL16(kgp,              smem + 16384 + (2 * w) * 1024);
        GLL16(kgp + 8 * HDIM,   smem + 16384 + (2 * w + 1) * 1024);
        GLL16(vgp,              smem + 24576 + (2 * w) * 1024);
        GLL16(vgp + 8 * N_DIM,  smem + 24576 + (2 * w + 1) * 1024);
        kgp += 64 * HDIM;
        vgp += 64;
        ATTN_VMCNT4();
        tile(16384);
    }
    ATTN_BARRIER();
    GLL16(kgp,              smem + 32768 + (2 * w) * 1024);
    GLL16(kgp + 8 * HDIM,   smem + 32768 + (2 * w + 1) * 1024);
    GLL16(vgp,              smem + 40960 + (2 * w) * 1024);
    GLL16(vgp + 8 * N_DIM,  smem + 40960 + (2 * w + 1) * 1024);
    ATTN_VMCNT4();
    tile(0);
    ATTN_BARRIER();
    ATTN_VMCNT0();
    tile(16384);

    #undef ATTN_BARRIER
    #undef ATTN_VMCNT4
    #undef ATTN_VMCNT0

    // ---- l reduce + write O strip (bf16, swizzled) ----
    float l_r = l_part + __shfl_xor(l_part, 32);
    float oinv = 1.f / l_r;
    #pragma unroll
    for (int db = 0; db < 2; ++db) {
        const f32x16& o = db ? oacc1 : oacc0;
        #pragma unroll
        for (int j = 0; j < 4; ++j) {
            unsigned lo = BFPACK(o[4 * j] * oinv,     o[4 * j + 1] * oinv);
            unsigned hi = BFPACK(o[4 * j + 2] * oinv, o[4 * j + 3] * oinv);
            *(unsigned long long*)(strip + ((db * 64 + h * 8 + 16 * j) ^ kswz)) =
                (unsigned long long)lo | ((unsigned long long)hi << 32);
        }
    }
    __syncthreads();
    // ---- coalesced global write: at [b][n][c] ----
    #pragma unroll
    for (int i = 0; i < 4; ++i) {
        int idx = tid + i * 256;           // 1024 chunks = 128 rows x 8x16B
        int row = idx >> 3, ch = idx & 7;
        bf16x8 v = *(const bf16x8*)(smem + row * 128 + ((ch * 16) ^ ((row & 7) << 4)));
        *(bf16x8*)&at[((size_t)(b * N_DIM + q0 + row)) * C_DIM + hh * HDIM + ch * 8] = v;
    }
}

// ---------------------------------------------------------------------------
extern "C" void kernel_launch(void* const* d_in, const int* in_sizes, int n_in,
                              void* d_out, int out_size, void* d_ws, size_t ws_size,
                              hipStream_t stream) {
    (void)in_sizes; (void)n_in; (void)out_size; (void)ws_size;
    const float* x     = (const float*)d_in[0];
    const float* gam   = (const float*)d_in[1];
    const float* bet   = (const float*)d_in[2];
    const float* q_w   = (const float*)d_in[3];
    const float* q_b   = (const float*)d_in[4];
    const float* k_w   = (const float*)d_in[5];
    const float* k_b   = (const float*)d_in[6];
    const float* v_w   = (const float*)d_in[7];
    const float* v_b   = (const float*)d_in[8];
    const float* p_w   = (const float*)d_in[9];
    const float* p_b   = (const float*)d_in[10];
    float* out = (float*)d_out;

    const size_t MB = 1 << 20;
    char* wsb = (char*)d_ws;
    unsigned short* ht  = (unsigned short*)(wsb);              // 8 MB  [8192][512]
    unsigned short* wqb = (unsigned short*)(wsb + 8 * MB);     // 4 x 512KB contiguous (q,k,v,p)
    unsigned short* wpb = (unsigned short*)(wsb + 9 * MB + 512 * 1024);
    float*          partial = (float*)(wsb + 10 * MB);         // 2 KB
    unsigned short* qt  = (unsigned short*)(wsb + 11 * MB);    // 8 MB [bh][n][d]
    unsigned short* kt  = (unsigned short*)(wsb + 19 * MB);    // 8 MB
    unsigned short* vt  = (unsigned short*)(wsb + 27 * MB);    // 8 MB [b][c][n]
    unsigned short* at  = (unsigned short*)(wsb + 35 * MB);    // 8 MB [b][n][c]

    gn_stats<<<B_DIM * NGRP * 2, 256, 0, stream>>>(x, partial);
    gn_apply_t<<<dim3(N_DIM / 64, C_DIM / 64, B_DIM), 256, 0, stream>>>(x, partial, gam, bet, ht);

    cast4_bf16<<<dim3(128, 4), 256, 0, stream>>>(q_w, k_w, v_w, p_w, wqb);

    const float escale = 0.044194173824159216f * 1.4426950408889634f;  // scale*log2(e)
    conv_qkv<<<dim3(B_DIM * N_DIM / 128, C_DIM / 64), 512, 0, stream>>>(
        wqb, q_b, k_b, v_b, ht, qt, kt, vt, escale);

    attn_kernel<<<512, 256, 0, stream>>>(qt, kt, vt, at);

    conv_proj<<<dim3(B_DIM * N_DIM / 128, C_DIM / 64), 256, 0, stream>>>(wpb, p_b, at, x, out);
}

// Round 16
// 101.740 us; speedup vs baseline: 1.1911x; 1.1438x over previous
//
#include <hip/hip_runtime.h>
#include <hip/hip_bf16.h>
#include <math.h>

#define C_DIM 512
#define N_DIM 2048
#define B_DIM 4
#define NGRP 32
#define GCH 16          // channels per group
#define NHEAD 8
#define HDIM 64
#define EPSV 1e-6f

using f32x4  = __attribute__((ext_vector_type(4))) float;
using bf16x8 = __attribute__((ext_vector_type(8))) short;   // 8 bf16 raw bits (4 VGPRs)

// async global->LDS, 16B per lane; LDS dest = wave-uniform base + lane*16
#define GLL16(gp, lp) __builtin_amdgcn_global_load_lds( \
    (const __attribute__((address_space(1))) unsigned int*)(gp), \
    (__attribute__((address_space(3))) unsigned int*)(lp), 16, 0, 0)

// pack high-16 (truncated bf16) of two f32s: lo16 = a, hi16 = b
#define BFPACK(a, b) __builtin_amdgcn_perm(__float_as_uint(b), __float_as_uint(a), 0x07060302u)

// raw v_exp_f32 (2^x, 1ulp) — avoids OCML range-check wrapper
#define EXP2R(x) __builtin_amdgcn_exp2f(x)

static __device__ __forceinline__ unsigned short f2bf(float f) {
    union { __hip_bfloat16 h; unsigned short u; } cv;
    cv.h = __float2bfloat16(f);
    return cv.u;
}

// ---------------------------------------------------------------------------
// gn_stats: 2 blocks per (b,group) half-slab; partial sums.
// ---------------------------------------------------------------------------
__global__ __launch_bounds__(256) void gn_stats(const float* __restrict__ x,
                                                float* __restrict__ partial) {
    const int HSZ = GCH * N_DIM / 2;        // 16384 floats per half
    int blk = blockIdx.x;                   // 0..255
    const float4* x4 = (const float4*)(x + (size_t)blk * HSZ);
    int tid = threadIdx.x;

    float s = 0.f, ss = 0.f;
    #pragma unroll
    for (int it = 0; it < HSZ / 4 / 256; ++it) {
        float4 v = x4[tid + it * 256];
        s  += v.x + v.y + v.z + v.w;
        ss += v.x * v.x + v.y * v.y + v.z * v.z + v.w * v.w;
    }
    __shared__ float rs[256], rss[256];
    rs[tid] = s; rss[tid] = ss;
    __syncthreads();
    for (int off = 128; off > 0; off >>= 1) {
        if (tid < off) { rs[tid] += rs[tid + off]; rss[tid] += rss[tid + off]; }
        __syncthreads();
    }
    if (tid == 0) {
        partial[blk * 2]     = rs[0];
        partial[blk * 2 + 1] = rss[0];
    }
}

// ---------------------------------------------------------------------------
// gn_apply_t: x [b][c][n] fp32 -> ht [(b*n)][c] bf16 (normalized, transposed).
// ---------------------------------------------------------------------------
__global__ __launch_bounds__(256) void gn_apply_t(const float* __restrict__ x,
                                                  const float* __restrict__ partial,
                                                  const float* __restrict__ gamma,
                                                  const float* __restrict__ beta,
                                                  unsigned short* __restrict__ ht) {
    __shared__ char smem[8192];     // [64 n][64 c] bf16, rows 128B, XOR-swizzled
    const float GSZI = 1.f / (GCH * N_DIM);
    int n0 = blockIdx.x * 64, c0 = blockIdx.y * 64, b = blockIdx.z;
    int tid = threadIdx.x;
    #pragma unroll
    for (int it = 0; it < 4; ++it) {
        int idx = tid + it * 256;
        int ci = idx >> 4, n4 = (idx & 15) << 2;
        int cg = c0 + ci, grp = cg >> 4;
        int bg = b * NGRP + grp;
        float s  = partial[bg * 4]     + partial[bg * 4 + 2];
        float ss = partial[bg * 4 + 1] + partial[bg * 4 + 3];
        float mean = s * GSZI;
        float var  = ss * GSZI - mean * mean;
        float rstd = rsqrtf(var + EPSV);
        float ga = gamma[cg] * rstd, be = beta[cg] - mean * ga;
        float4 v = *(const float4*)&x[((size_t)b * C_DIM + cg) * N_DIM + n0 + n4];
        float vals[4] = {v.x, v.y, v.z, v.w};
        #pragma unroll
        for (int j = 0; j < 4; ++j) {
            int nl = n4 + j;
            *(unsigned short*)(smem + nl * 128 + ((ci * 2) ^ ((nl & 7) << 4))) =
                f2bf(vals[j] * ga + be);
        }
    }
    __syncthreads();
    #pragma unroll
    for (int i = 0; i < 2; ++i) {
        int idx = tid + i * 256;       // 512 chunks = 64 rows x 8x16B
        int row = idx >> 3, ch = idx & 7;
        bf16x8 v = *(const bf16x8*)(smem + row * 128 + ((ch * 16) ^ ((row & 7) << 4)));
        *(bf16x8*)&ht[((size_t)(b * N_DIM + n0 + row)) * C_DIM + c0 + ch * 8] = v;
    }
}

// ---------------------------------------------------------------------------
// cast4: fp32 -> bf16 for the four 512x512 weights in one launch.
// ---------------------------------------------------------------------------
__global__ __launch_bounds__(256) void cast4_bf16(const float* __restrict__ s0,
                                                  const float* __restrict__ s1,
                                                  const float* __restrict__ s2,
                                                  const float* __restrict__ s3,
                                                  unsigned short* __restrict__ dst) {
    int which = blockIdx.y;
    const float* src = (which == 0) ? s0 : (which == 1) ? s1 : (which == 2) ? s2 : s3;
    size_t idx = (size_t)blockIdx.x * 256 + threadIdx.x;
    const float4* s4 = (const float4*)src;
    float4 a = s4[idx * 2], b = s4[idx * 2 + 1];
    bf16x8 o;
    o[0] = (short)f2bf(a.x); o[1] = (short)f2bf(a.y);
    o[2] = (short)f2bf(a.z); o[3] = (short)f2bf(a.w);
    o[4] = (short)f2bf(b.x); o[5] = (short)f2bf(b.y);
    o[6] = (short)f2bf(b.z); o[7] = (short)f2bf(b.w);
    *(bf16x8*)&dst[(size_t)which * 262144 + idx * 8] = o;
}

// ---------------------------------------------------------------------------
// conv_qkv v2: fused Q/K/V convs. (Unchanged.)
// ---------------------------------------------------------------------------
__global__ __launch_bounds__(512) void conv_qkv(const unsigned short* __restrict__ Wall,
                                                const float* __restrict__ q_b,
                                                const float* __restrict__ k_b,
                                                const float* __restrict__ v_b,
                                                const unsigned short* __restrict__ ht,
                                                unsigned short* __restrict__ qt,
                                                unsigned short* __restrict__ kt,
                                                unsigned short* __restrict__ vt,
                                                float escale) {
    __shared__ char smem[40960];     // Bs 16KB | As_q 8KB | As_k 8KB | As_v 8KB

    int bn0 = blockIdx.x * 128;      // flattened b*N + n
    int bo  = blockIdx.y * 64;
    int tid = threadIdx.x;
    int L = tid & 63, w = tid >> 6;
    int g = L >> 4, c = L & 15;
    int wr = w >> 2, wc = w & 3;

    f32x4 acc[3][2][2];
    #pragma unroll
    for (int w3 = 0; w3 < 3; ++w3)
        #pragma unroll
        for (int t = 0; t < 2; ++t)
            #pragma unroll
            for (int u = 0; u < 2; ++u) acc[w3][t][u] = f32x4{0.f, 0.f, 0.f, 0.f};

    for (int k0 = 0; k0 < C_DIM; k0 += 64) {
        if (w < 4) {
            #pragma unroll
            for (int i = 0; i < 4; ++i) {
                int j = w * 4 + i;
                int row = j * 8 + (L >> 3);
                int sl = (L & 7) ^ (row & 7);
                GLL16(ht + (size_t)(bn0 + row) * C_DIM + k0 + sl * 8, smem + j * 1024);
            }
        } else {
            #pragma unroll
            for (int i = 0; i < 6; ++i) {
                int j = (w - 4) * 6 + i;
                int w3 = j >> 3, jj = j & 7;
                int row = jj * 8 + (L >> 3);
                int sl = (L & 7) ^ (row & 7);
                GLL16(Wall + (size_t)w3 * 262144 + (size_t)(bo + row) * C_DIM + k0 + sl * 8,
                      smem + 16384 + j * 1024);
            }
        }
        __syncthreads();

        bf16x8 bfr[2][2];
        #pragma unroll
        for (int u = 0; u < 2; ++u) {
            int row = wc * 32 + u * 16 + c;
            #pragma unroll
            for (int ks = 0; ks < 2; ++ks)
                bfr[u][ks] = *(const bf16x8*)(smem + row * 128 +
                                              ((g * 16 + ks * 64) ^ ((row & 7) << 4)));
        }
        #pragma unroll
        for (int w3 = 0; w3 < 3; ++w3) {
            char* As = smem + 16384 + w3 * 8192;
            bf16x8 af[2][2];
            #pragma unroll
            for (int t = 0; t < 2; ++t) {
                int row = wr * 32 + t * 16 + c;
                #pragma unroll
                for (int ks = 0; ks < 2; ++ks)
                    af[t][ks] = *(const bf16x8*)(As + row * 128 +
                                                 ((g * 16 + ks * 64) ^ ((row & 7) << 4)));
            }
            #pragma unroll
            for (int ks = 0; ks < 2; ++ks)
                #pragma unroll
                for (int t = 0; t < 2; ++t)
                    #pragma unroll
                    for (int u = 0; u < 2; ++u)
                        acc[w3][t][u] = __builtin_amdgcn_mfma_f32_16x16x32_bf16(
                            af[t][ks], bfr[u][ks], acc[w3][t][u], 0, 0, 0);
        }
        __syncthreads();
    }

    int b  = bn0 >> 11;              // N_DIM = 2048
    int nb = bn0 & (N_DIM - 1);
    int hh = bo >> 6;
    int bh = b * NHEAD + hh;

    #pragma unroll
    for (int t = 0; t < 2; ++t)
        #pragma unroll
        for (int r = 0; r < 4; ++r) {
            int m = bo + wr * 32 + t * 16 + g * 4 + r;
            float bi = v_b[m];
            #pragma unroll
            for (int u = 0; u < 2; ++u) {
                int n = nb + wc * 32 + u * 16 + c;
                vt[((size_t)b * C_DIM + m) * N_DIM + n] = f2bf(acc[2][t][u][r] + bi);
            }
        }

    char* Ts = smem;                 // [128 n][64 d] swz
    #pragma unroll
    for (int pass = 0; pass < 2; ++pass) {
        const float* bias = pass ? k_b : q_b;
        float esc = pass ? 1.0f : escale;
        unsigned short* dst = pass ? kt : qt;
        __syncthreads();
        #pragma unroll
        for (int t = 0; t < 2; ++t)
            #pragma unroll
            for (int r = 0; r < 4; ++r) {
                int ml = wr * 32 + t * 16 + g * 4 + r;   // d
                float bi = bias[bo + ml];
                #pragma unroll
                for (int u = 0; u < 2; ++u) {
                    int nl = wc * 32 + u * 16 + c;       // 0..127
                    *(unsigned short*)(Ts + nl * 128 + ((ml * 2) ^ ((nl & 7) << 4))) =
                        f2bf((acc[pass][t][u][r] + bi) * esc);
                }
            }
        __syncthreads();
        #pragma unroll
        for (int i = 0; i < 2; ++i) {
            int idx = tid + i * 512;     // 1024 chunks = 128 rows x 8x16B
            int row = idx >> 3, ch = idx & 7;
            bf16x8 v = *(const bf16x8*)(Ts + row * 128 + ((ch * 16) ^ ((row & 7) << 4)));
            *(bf16x8*)&dst[((size_t)bh * N_DIM + nb + row) * HDIM + ch * 8] = v;
        }
    }
}

// ---------------------------------------------------------------------------
// conv_proj: out fp32 [b][c][n] + residual. (Unchanged.)
// ---------------------------------------------------------------------------
__global__ __launch_bounds__(256) void conv_proj(const unsigned short* __restrict__ Wb,
                                                 const float* __restrict__ bias,
                                                 const unsigned short* __restrict__ Bsrc,
                                                 const float* __restrict__ res,
                                                 float* __restrict__ outf) {
    __shared__ char smem[24576];
    int bn0 = blockIdx.x * 128;
    int bo  = blockIdx.y * 64;
    int tid = threadIdx.x;
    int L = tid & 63, w = tid >> 6;
    int g = L >> 4, c = L & 15;
    int wr = w >> 1, wc = w & 1;

    f32x4 acc[2][4];
    #pragma unroll
    for (int t = 0; t < 2; ++t)
        #pragma unroll
        for (int u = 0; u < 4; ++u) acc[t][u] = f32x4{0.f, 0.f, 0.f, 0.f};

    for (int k0 = 0; k0 < C_DIM; k0 += 64) {
        #pragma unroll
        for (int i = 0; i < 2; ++i) {
            int j = w * 2 + i;
            int ra = j * 8 + (L >> 3);
            int sl = (L & 7) ^ (ra & 7);
            GLL16(Wb + (size_t)(bo + ra) * C_DIM + k0 + sl * 8, smem + j * 1024);
        }
        #pragma unroll
        for (int i = 0; i < 4; ++i) {
            int j = w * 4 + i;
            int rb = j * 8 + (L >> 3);
            int sl = (L & 7) ^ (rb & 7);
            GLL16(Bsrc + (size_t)(bn0 + rb) * C_DIM + k0 + sl * 8, smem + 8192 + j * 1024);
        }
        __syncthreads();

        bf16x8 af[2][2], bfr[4][2];
        #pragma unroll
        for (int t = 0; t < 2; ++t) {
            int row = wr * 32 + t * 16 + c;
            #pragma unroll
            for (int ks = 0; ks < 2; ++ks)
                af[t][ks] = *(const bf16x8*)(smem + row * 128 +
                                             ((g * 16 + ks * 64) ^ ((row & 7) << 4)));
        }
        #pragma unroll
        for (int u = 0; u < 4; ++u) {
            int row = wc * 64 + u * 16 + c;
            #pragma unroll
            for (int ks = 0; ks < 2; ++ks)
                bfr[u][ks] = *(const bf16x8*)(smem + 8192 + row * 128 +
                                              ((g * 16 + ks * 64) ^ ((row & 7) << 4)));
        }
        #pragma unroll
        for (int ks = 0; ks < 2; ++ks)
            #pragma unroll
            for (int t = 0; t < 2; ++t)
                #pragma unroll
                for (int u = 0; u < 4; ++u)
                    acc[t][u] = __builtin_amdgcn_mfma_f32_16x16x32_bf16(
                        af[t][ks], bfr[u][ks], acc[t][u], 0, 0, 0);
        __syncthreads();
    }

    int b  = bn0 >> 11;
    int nb = bn0 & (N_DIM - 1);
    #pragma unroll
    for (int t = 0; t < 2; ++t)
        #pragma unroll
        for (int r = 0; r < 4; ++r) {
            int m = bo + wr * 32 + t * 16 + g * 4 + r;
            float bi = bias[m];
            #pragma unroll
            for (int u = 0; u < 4; ++u) {
                int n = nb + wc * 64 + u * 16 + c;
                size_t off = ((size_t)b * C_DIM + m) * N_DIM + n;
                outf[off] = acc[t][u][r] + bi + res[off];
            }
        }
}

// ---------------------------------------------------------------------------
// MFMA bf16 flash attention, swapped-operand form. 8 waves, QBLK=128.
// R16: R13 structure (best) + raw v_exp_f32 via __builtin_amdgcn_exp2f
// (avoids OCML exp2 wrapper bloat) + v_rcp for 1/l. XCD remap + counted
// vmcnt retained.
// ---------------------------------------------------------------------------
__global__ __launch_bounds__(512, 4) void attn_kernel(const unsigned short* __restrict__ Qt,
                                                      const unsigned short* __restrict__ Kt,
                                                      const unsigned short* __restrict__ Vt,
                                                      unsigned short* __restrict__ at) {
    __shared__ char smem[49152];
    // [0,16K): Q staging -> P/O strips; [16K,32K): buf0 (K|V); [32K,48K): buf1

    // ---- XCD-aware remap (grid = 512 linear blocks, XCD = d % 8) ----
    int d = blockIdx.x;                // 0..511 dispatch id
    int xcd = d & 7;
    int slot = d >> 3;                 // 0..63 within XCD
    int bh = xcd + 8 * (slot >> 4);    // heads {xcd, xcd+8, xcd+16, xcd+24}
    int q0 = (slot & 15) * 128;

    int b = bh >> 3, hh = bh & 7;
    int tid = threadIdx.x;
    int L = tid & 63, w = tid >> 6;        // 8 waves
    int g = L >> 4, c = L & 15;

    const unsigned short* Qh = Qt + (size_t)bh * N_DIM * HDIM;
    const unsigned short* Kh = Kt + (size_t)bh * N_DIM * HDIM;
    const unsigned short* Vh = Vt + (size_t)bh * HDIM * N_DIM;

    // ---- prologue: stage Q (16 x 1KB) + K/V tile 0 into buf0, all async ----
    #pragma unroll
    for (int i = 0; i < 2; ++i) {
        int j = w * 2 + i;
        int row = j * 8 + (L >> 3);        // 0..127
        int sl = (L & 7) ^ (row & 7);
        GLL16(Qh + (size_t)(q0 + row) * HDIM + sl * 8, smem + j * 1024);
    }
    int srow = w * 8 + (L >> 3);           // staging row 0..63
    int ssl  = (L & 7) ^ (srow & 7);
    GLL16(Kh + (size_t)srow * HDIM + ssl * 8, smem + 16384 + w * 1024);
    GLL16(Vh + (size_t)srow * N_DIM + ssl * 8, smem + 24576 + w * 1024);
    __syncthreads();                       // full drain: Q + tile0 ready

    // ---- hoisted addresses ----
    int csw = (c & 7) << 4;
    char* kb0 = smem + 16384 + c * 128 + ((g * 16) ^ csw);        // K frag ks=0
    char* kb1 = smem + 16384 + c * 128 + ((g * 16 + 64) ^ csw);   // K frag ks=1
    char* pb  = smem + (w * 16 + c) * 128;                        // wave-private strip
    char* pw0 = pb + ((g * 8) ^ csw);
    char* pw1 = pb + ((32 + g * 8) ^ csw);
    char* pw2 = pb + ((64 + g * 8) ^ csw);
    char* pw3 = pb + ((96 + g * 8) ^ csw);
    char* pr0 = pb + ((g * 16) ^ csw);
    char* pr1 = pb + ((64 + g * 16) ^ csw);

    // Q fragments from strip region (same addresses as pr0/pr1)
    bf16x8 qf[2];
    qf[0] = *(const bf16x8*)pr0;
    qf[1] = *(const bf16x8*)pr1;

    // staging global pointers -> tile 1
    const unsigned short* kgp = Kh + (size_t)(64 + srow) * HDIM + ssl * 8;
    const unsigned short* vgp = Vh + (size_t)srow * N_DIM + 64 + ssl * 8;

    f32x4 oacc[4];
    #pragma unroll
    for (int t = 0; t < 4; ++t) oacc[t] = f32x4{0.f, 0.f, 0.f, 0.f};
    float m_r = -INFINITY, l_part = 0.f;

    auto tile = [&](int BOFF) {
        // ---- S^T = K Q^T : D[kpos=16t+4g+r][q=16w+c] ----
        f32x4 sacc[4];
        #pragma unroll
        for (int t = 0; t < 4; ++t) sacc[t] = f32x4{0.f, 0.f, 0.f, 0.f};
        __builtin_amdgcn_s_setprio(1);
        #pragma unroll
        for (int t = 0; t < 4; ++t) {
            bf16x8 kf0 = *(const bf16x8*)(kb0 + BOFF + t * 2048);
            bf16x8 kf1 = *(const bf16x8*)(kb1 + BOFF + t * 2048);
            sacc[t] = __builtin_amdgcn_mfma_f32_16x16x32_bf16(kf0, qf[0], sacc[t], 0, 0, 0);
            sacc[t] = __builtin_amdgcn_mfma_f32_16x16x32_bf16(kf1, qf[1], sacc[t], 0, 0, 0);
        }
        __builtin_amdgcn_s_setprio(0);

        // ---- softmax over kpos (exp2 domain); zero-shfl steady state ----
        float t0 = fmaxf(fmaxf(sacc[0][0], sacc[0][1]), sacc[0][2]);
        float t1 = fmaxf(fmaxf(sacc[0][3], sacc[1][0]), sacc[1][1]);
        float t2 = fmaxf(fmaxf(sacc[1][2], sacc[1][3]), sacc[2][0]);
        float t3 = fmaxf(fmaxf(sacc[2][1], sacc[2][2]), sacc[2][3]);
        float t4 = fmaxf(fmaxf(sacc[3][0], sacc[3][1]), sacc[3][2]);
        float mloc = fmaxf(fmaxf(fmaxf(t0, t1), fmaxf(t2, t3)), fmaxf(t4, sacc[3][3]));
        if (!__all(mloc - m_r <= 6.0f)) {       // rare: row max grew
            mloc = fmaxf(mloc, __shfl_xor(mloc, 16));
            mloc = fmaxf(mloc, __shfl_xor(mloc, 32));
            float mn = fmaxf(m_r, mloc);
            float fac = EXP2R(m_r - mn);
            m_r = mn;
            l_part *= fac;
            #pragma unroll
            for (int t = 0; t < 4; ++t) oacc[t] = oacc[t] * fac;
        }
        f32x4 m4 = {m_r, m_r, m_r, m_r};
        f32x4 p[4];
        #pragma unroll
        for (int t = 0; t < 4; ++t) {
            f32x4 dd = sacc[t] - m4;
            p[t][0] = EXP2R(dd[0]);
            p[t][1] = EXP2R(dd[1]);
            p[t][2] = EXP2R(dd[2]);
            p[t][3] = EXP2R(dd[3]);
        }
        f32x4 racc = (p[0] + p[1]) + (p[2] + p[3]);
        l_part += (racc[0] + racc[1]) + (racc[2] + racc[3]);

        unsigned pk[4][2];
        #pragma unroll
        for (int t = 0; t < 4; ++t) {
            pk[t][0] = BFPACK(p[t][0], p[t][1]);
            pk[t][1] = BFPACK(p[t][2], p[t][3]);
        }

        // ---- P^T strip (wave-private) ----
        *(unsigned long long*)pw0 = (unsigned long long)pk[0][0] | ((unsigned long long)pk[0][1] << 32);
        *(unsigned long long*)pw1 = (unsigned long long)pk[1][0] | ((unsigned long long)pk[1][1] << 32);
        *(unsigned long long*)pw2 = (unsigned long long)pk[2][0] | ((unsigned long long)pk[2][1] << 32);
        *(unsigned long long*)pw3 = (unsigned long long)pk[3][0] | ((unsigned long long)pk[3][1] << 32);

        // ---- O^T += V^T P^T ----
        __builtin_amdgcn_s_setprio(1);
        {
            bf16x8 pf0 = *(const bf16x8*)pr0;
            #pragma unroll
            for (int t = 0; t < 4; ++t) {
                bf16x8 vf = *(const bf16x8*)(kb0 + BOFF + 8192 + t * 2048);
                oacc[t] = __builtin_amdgcn_mfma_f32_16x16x32_bf16(vf, pf0, oacc[t], 0, 0, 0);
            }
            bf16x8 pf1 = *(const bf16x8*)pr1;
            #pragma unroll
            for (int t = 0; t < 4; ++t) {
                bf16x8 vf = *(const bf16x8*)(kb1 + BOFF + 8192 + t * 2048);
                oacc[t] = __builtin_amdgcn_mfma_f32_16x16x32_bf16(vf, pf1, oacc[t], 0, 0, 0);
            }
        }
        __builtin_amdgcn_s_setprio(0);
    };

    // T4 pipeline helpers: raw barrier + compiler fence; counted vmcnt.
    #define ATTN_BARRIER() do { \
        __builtin_amdgcn_s_barrier(); \
        asm volatile("" ::: "memory"); \
    } while (0)
    #define ATTN_VMCNT2() do { \
        asm volatile("s_waitcnt vmcnt(2)" ::: "memory"); \
        __builtin_amdgcn_sched_barrier(0); \
    } while (0)
    #define ATTN_VMCNT0() do { \
        asm volatile("s_waitcnt vmcnt(0)" ::: "memory"); \
        __builtin_amdgcn_sched_barrier(0); \
    } while (0)

    // main loop: tiles 0..29 (paired), stage(i+1) in flight across barrier
    for (int i = 0; i < 15; ++i) {
        ATTN_BARRIER();
        GLL16(kgp, smem + 32768 + w * 1024);
        GLL16(vgp, smem + 40960 + w * 1024);
        kgp += 64 * HDIM;
        vgp += 64;
        ATTN_VMCNT2();
        tile(0);
        ATTN_BARRIER();
        GLL16(kgp, smem + 16384 + w * 1024);
        GLL16(vgp, smem + 24576 + w * 1024);
        kgp += 64 * HDIM;
        vgp += 64;
        ATTN_VMCNT2();
        tile(16384);
    }
    // tile 30 (buf0); stage tile 31 -> buf1
    ATTN_BARRIER();
    GLL16(kgp, smem + 32768 + w * 1024);
    GLL16(vgp, smem + 40960 + w * 1024);
    ATTN_VMCNT2();
    tile(0);
    // tile 31 (buf1); no more staging -> full drain
    ATTN_BARRIER();
    ATTN_VMCNT0();
    tile(16384);

    #undef ATTN_BARRIER
    #undef ATTN_VMCNT2
    #undef ATTN_VMCNT0

    // ---- deferred l reduction + epilogue (wave-private strip) ----
    float l_r = l_part;
    l_r += __shfl_xor(l_r, 16);
    l_r += __shfl_xor(l_r, 32);
    float oinv = __builtin_amdgcn_rcpf(l_r);
    {
        unsigned lo, hi;
        lo = BFPACK(oacc[0][0] * oinv, oacc[0][1] * oinv);
        hi = BFPACK(oacc[0][2] * oinv, oacc[0][3] * oinv);
        *(unsigned long long*)pw0 = (unsigned long long)lo | ((unsigned long long)hi << 32);
        lo = BFPACK(oacc[1][0] * oinv, oacc[1][1] * oinv);
        hi = BFPACK(oacc[1][2] * oinv, oacc[1][3] * oinv);
        *(unsigned long long*)pw1 = (unsigned long long)lo | ((unsigned long long)hi << 32);
        lo = BFPACK(oacc[2][0] * oinv, oacc[2][1] * oinv);
        hi = BFPACK(oacc[2][2] * oinv, oacc[2][3] * oinv);
        *(unsigned long long*)pw2 = (unsigned long long)lo | ((unsigned long long)hi << 32);
        lo = BFPACK(oacc[3][0] * oinv, oacc[3][1] * oinv);
        hi = BFPACK(oacc[3][2] * oinv, oacc[3][3] * oinv);
        *(unsigned long long*)pw3 = (unsigned long long)lo | ((unsigned long long)hi << 32);
    }
    char* wbase = smem + w * 2048;         // wave's 16 rows
    #pragma unroll
    for (int i = 0; i < 2; ++i) {
        int idx = L + i * 64;              // 128 chunks = 16 rows x 8x16B
        int row = idx >> 3, ch = idx & 7;
        bf16x8 v = *(const bf16x8*)(wbase + row * 128 + ((ch * 16) ^ ((row & 7) << 4)));
        *(bf16x8*)&at[((size_t)(b * N_DIM + q0 + w * 16 + row)) * C_DIM + hh * HDIM + ch * 8] = v;
    }
}

// ---------------------------------------------------------------------------
extern "C" void kernel_launch(void* const* d_in, const int* in_sizes, int n_in,
                              void* d_out, int out_size, void* d_ws, size_t ws_size,
                              hipStream_t stream) {
    (void)in_sizes; (void)n_in; (void)out_size; (void)ws_size;
    const float* x     = (const float*)d_in[0];
    const float* gam   = (const float*)d_in[1];
    const float* bet   = (const float*)d_in[2];
    const float* q_w   = (const float*)d_in[3];
    const float* q_b   = (const float*)d_in[4];
    const float* k_w   = (const float*)d_in[5];
    const float* k_b   = (const float*)d_in[6];
    const float* v_w   = (const float*)d_in[7];
    const float* v_b   = (const float*)d_in[8];
    const float* p_w   = (const float*)d_in[9];
    const float* p_b   = (const float*)d_in[10];
    float* out = (float*)d_out;

    const size_t MB = 1 << 20;
    char* wsb = (char*)d_ws;
    unsigned short* ht  = (unsigned short*)(wsb);              // 8 MB  [8192][512]
    unsigned short* wqb = (unsigned short*)(wsb + 8 * MB);     // 4 x 512KB contiguous (q,k,v,p)
    unsigned short* wpb = (unsigned short*)(wsb + 9 * MB + 512 * 1024);
    float*          partial = (float*)(wsb + 10 * MB);         // 2 KB
    unsigned short* qt  = (unsigned short*)(wsb + 11 * MB);    // 8 MB [bh][n][d]
    unsigned short* kt  = (unsigned short*)(wsb + 19 * MB);    // 8 MB
    unsigned short* vt  = (unsigned short*)(wsb + 27 * MB);    // 8 MB [b][c][n]
    unsigned short* at  = (unsigned short*)(wsb + 35 * MB);    // 8 MB [b][n][c]

    gn_stats<<<B_DIM * NGRP * 2, 256, 0, stream>>>(x, partial);
    gn_apply_t<<<dim3(N_DIM / 64, C_DIM / 64, B_DIM), 256, 0, stream>>>(x, partial, gam, bet, ht);

    cast4_bf16<<<dim3(128, 4), 256, 0, stream>>>(q_w, k_w, v_w, p_w, wqb);

    const float escale = 0.044194173824159216f * 1.4426950408889634f;  // scale*log2(e)
    conv_qkv<<<dim3(B_DIM * N_DIM / 128, C_DIM / 64), 512, 0, stream>>>(
        wqb, q_b, k_b, v_b, ht, qt, kt, vt, escale);

    attn_kernel<<<512, 512, 0, stream>>>(qt, kt, vt, at);

    conv_proj<<<dim3(B_DIM * N_DIM / 128, C_DIM / 64), 256, 0, stream>>>(wpb, p_b, at, x, out);
}

// Round 17
// 101.663 us; speedup vs baseline: 1.1920x; 1.0008x over previous
//
#include <hip/hip_runtime.h>
#include <hip/hip_bf16.h>
#include <math.h>

#define C_DIM 512
#define N_DIM 2048
#define B_DIM 4
#define NGRP 32
#define GCH 16          // channels per group
#define NHEAD 8
#define HDIM 64
#define EPSV 1e-6f

using f32x4  = __attribute__((ext_vector_type(4))) float;
using bf16x8 = __attribute__((ext_vector_type(8))) short;   // 8 bf16 raw bits (4 VGPRs)

// async global->LDS, 16B per lane; LDS dest = wave-uniform base + lane*16
#define GLL16(gp, lp) __builtin_amdgcn_global_load_lds( \
    (const __attribute__((address_space(1))) unsigned int*)(gp), \
    (__attribute__((address_space(3))) unsigned int*)(lp), 16, 0, 0)

// pack high-16 (truncated bf16) of two f32s: lo16 = a, hi16 = b
#define BFPACK(a, b) __builtin_amdgcn_perm(__float_as_uint(b), __float_as_uint(a), 0x07060302u)

// raw v_exp_f32 (2^x, 1ulp) — avoids OCML range-check wrapper
#define EXP2R(x) __builtin_amdgcn_exp2f(x)

static __device__ __forceinline__ unsigned short f2bf(float f) {
    union { __hip_bfloat16 h; unsigned short u; } cv;
    cv.h = __float2bfloat16(f);
    return cv.u;
}

// ---------------------------------------------------------------------------
// gn_stats: 2 blocks per (b,group) half-slab; partial sums.
// ---------------------------------------------------------------------------
__global__ __launch_bounds__(256) void gn_stats(const float* __restrict__ x,
                                                float* __restrict__ partial) {
    const int HSZ = GCH * N_DIM / 2;        // 16384 floats per half
    int blk = blockIdx.x;                   // 0..255
    const float4* x4 = (const float4*)(x + (size_t)blk * HSZ);
    int tid = threadIdx.x;

    float s = 0.f, ss = 0.f;
    #pragma unroll
    for (int it = 0; it < HSZ / 4 / 256; ++it) {
        float4 v = x4[tid + it * 256];
        s  += v.x + v.y + v.z + v.w;
        ss += v.x * v.x + v.y * v.y + v.z * v.z + v.w * v.w;
    }
    __shared__ float rs[256], rss[256];
    rs[tid] = s; rss[tid] = ss;
    __syncthreads();
    for (int off = 128; off > 0; off >>= 1) {
        if (tid < off) { rs[tid] += rs[tid + off]; rss[tid] += rss[tid + off]; }
        __syncthreads();
    }
    if (tid == 0) {
        partial[blk * 2]     = rs[0];
        partial[blk * 2 + 1] = rss[0];
    }
}

// ---------------------------------------------------------------------------
// gn_apply_t: x [b][c][n] fp32 -> ht [(b*n)][c] bf16 (normalized, transposed).
// ---------------------------------------------------------------------------
__global__ __launch_bounds__(256) void gn_apply_t(const float* __restrict__ x,
                                                  const float* __restrict__ partial,
                                                  const float* __restrict__ gamma,
                                                  const float* __restrict__ beta,
                                                  unsigned short* __restrict__ ht) {
    __shared__ char smem[8192];     // [64 n][64 c] bf16, rows 128B, XOR-swizzled
    const float GSZI = 1.f / (GCH * N_DIM);
    int n0 = blockIdx.x * 64, c0 = blockIdx.y * 64, b = blockIdx.z;
    int tid = threadIdx.x;
    #pragma unroll
    for (int it = 0; it < 4; ++it) {
        int idx = tid + it * 256;
        int ci = idx >> 4, n4 = (idx & 15) << 2;
        int cg = c0 + ci, grp = cg >> 4;
        int bg = b * NGRP + grp;
        float s  = partial[bg * 4]     + partial[bg * 4 + 2];
        float ss = partial[bg * 4 + 1] + partial[bg * 4 + 3];
        float mean = s * GSZI;
        float var  = ss * GSZI - mean * mean;
        float rstd = rsqrtf(var + EPSV);
        float ga = gamma[cg] * rstd, be = beta[cg] - mean * ga;
        float4 v = *(const float4*)&x[((size_t)b * C_DIM + cg) * N_DIM + n0 + n4];
        float vals[4] = {v.x, v.y, v.z, v.w};
        #pragma unroll
        for (int j = 0; j < 4; ++j) {
            int nl = n4 + j;
            *(unsigned short*)(smem + nl * 128 + ((ci * 2) ^ ((nl & 7) << 4))) =
                f2bf(vals[j] * ga + be);
        }
    }
    __syncthreads();
    #pragma unroll
    for (int i = 0; i < 2; ++i) {
        int idx = tid + i * 256;       // 512 chunks = 64 rows x 8x16B
        int row = idx >> 3, ch = idx & 7;
        bf16x8 v = *(const bf16x8*)(smem + row * 128 + ((ch * 16) ^ ((row & 7) << 4)));
        *(bf16x8*)&ht[((size_t)(b * N_DIM + n0 + row)) * C_DIM + c0 + ch * 8] = v;
    }
}

// ---------------------------------------------------------------------------
// cast4: fp32 -> bf16 for the four 512x512 weights in one launch.
// ---------------------------------------------------------------------------
__global__ __launch_bounds__(256) void cast4_bf16(const float* __restrict__ s0,
                                                  const float* __restrict__ s1,
                                                  const float* __restrict__ s2,
                                                  const float* __restrict__ s3,
                                                  unsigned short* __restrict__ dst) {
    int which = blockIdx.y;
    const float* src = (which == 0) ? s0 : (which == 1) ? s1 : (which == 2) ? s2 : s3;
    size_t idx = (size_t)blockIdx.x * 256 + threadIdx.x;
    const float4* s4 = (const float4*)src;
    float4 a = s4[idx * 2], b = s4[idx * 2 + 1];
    bf16x8 o;
    o[0] = (short)f2bf(a.x); o[1] = (short)f2bf(a.y);
    o[2] = (short)f2bf(a.z); o[3] = (short)f2bf(a.w);
    o[4] = (short)f2bf(b.x); o[5] = (short)f2bf(b.y);
    o[6] = (short)f2bf(b.z); o[7] = (short)f2bf(b.w);
    *(bf16x8*)&dst[(size_t)which * 262144 + idx * 8] = o;
}

// ---------------------------------------------------------------------------
// conv_qkv v2: fused Q/K/V convs. (Unchanged.)
// ---------------------------------------------------------------------------
__global__ __launch_bounds__(512) void conv_qkv(const unsigned short* __restrict__ Wall,
                                                const float* __restrict__ q_b,
                                                const float* __restrict__ k_b,
                                                const float* __restrict__ v_b,
                                                const unsigned short* __restrict__ ht,
                                                unsigned short* __restrict__ qt,
                                                unsigned short* __restrict__ kt,
                                                unsigned short* __restrict__ vt,
                                                float escale) {
    __shared__ char smem[40960];     // Bs 16KB | As_q 8KB | As_k 8KB | As_v 8KB

    int bn0 = blockIdx.x * 128;      // flattened b*N + n
    int bo  = blockIdx.y * 64;
    int tid = threadIdx.x;
    int L = tid & 63, w = tid >> 6;
    int g = L >> 4, c = L & 15;
    int wr = w >> 2, wc = w & 3;

    f32x4 acc[3][2][2];
    #pragma unroll
    for (int w3 = 0; w3 < 3; ++w3)
        #pragma unroll
        for (int t = 0; t < 2; ++t)
            #pragma unroll
            for (int u = 0; u < 2; ++u) acc[w3][t][u] = f32x4{0.f, 0.f, 0.f, 0.f};

    for (int k0 = 0; k0 < C_DIM; k0 += 64) {
        if (w < 4) {
            #pragma unroll
            for (int i = 0; i < 4; ++i) {
                int j = w * 4 + i;
                int row = j * 8 + (L >> 3);
                int sl = (L & 7) ^ (row & 7);
                GLL16(ht + (size_t)(bn0 + row) * C_DIM + k0 + sl * 8, smem + j * 1024);
            }
        } else {
            #pragma unroll
            for (int i = 0; i < 6; ++i) {
                int j = (w - 4) * 6 + i;
                int w3 = j >> 3, jj = j & 7;
                int row = jj * 8 + (L >> 3);
                int sl = (L & 7) ^ (row & 7);
                GLL16(Wall + (size_t)w3 * 262144 + (size_t)(bo + row) * C_DIM + k0 + sl * 8,
                      smem + 16384 + j * 1024);
            }
        }
        __syncthreads();

        bf16x8 bfr[2][2];
        #pragma unroll
        for (int u = 0; u < 2; ++u) {
            int row = wc * 32 + u * 16 + c;
            #pragma unroll
            for (int ks = 0; ks < 2; ++ks)
                bfr[u][ks] = *(const bf16x8*)(smem + row * 128 +
                                              ((g * 16 + ks * 64) ^ ((row & 7) << 4)));
        }
        #pragma unroll
        for (int w3 = 0; w3 < 3; ++w3) {
            char* As = smem + 16384 + w3 * 8192;
            bf16x8 af[2][2];
            #pragma unroll
            for (int t = 0; t < 2; ++t) {
                int row = wr * 32 + t * 16 + c;
                #pragma unroll
                for (int ks = 0; ks < 2; ++ks)
                    af[t][ks] = *(const bf16x8*)(As + row * 128 +
                                                 ((g * 16 + ks * 64) ^ ((row & 7) << 4)));
            }
            #pragma unroll
            for (int ks = 0; ks < 2; ++ks)
                #pragma unroll
                for (int t = 0; t < 2; ++t)
                    #pragma unroll
                    for (int u = 0; u < 2; ++u)
                        acc[w3][t][u] = __builtin_amdgcn_mfma_f32_16x16x32_bf16(
                            af[t][ks], bfr[u][ks], acc[w3][t][u], 0, 0, 0);
        }
        __syncthreads();
    }

    int b  = bn0 >> 11;              // N_DIM = 2048
    int nb = bn0 & (N_DIM - 1);
    int hh = bo >> 6;
    int bh = b * NHEAD + hh;

    #pragma unroll
    for (int t = 0; t < 2; ++t)
        #pragma unroll
        for (int r = 0; r < 4; ++r) {
            int m = bo + wr * 32 + t * 16 + g * 4 + r;
            float bi = v_b[m];
            #pragma unroll
            for (int u = 0; u < 2; ++u) {
                int n = nb + wc * 32 + u * 16 + c;
                vt[((size_t)b * C_DIM + m) * N_DIM + n] = f2bf(acc[2][t][u][r] + bi);
            }
        }

    char* Ts = smem;                 // [128 n][64 d] swz
    #pragma unroll
    for (int pass = 0; pass < 2; ++pass) {
        const float* bias = pass ? k_b : q_b;
        float esc = pass ? 1.0f : escale;
        unsigned short* dst = pass ? kt : qt;
        __syncthreads();
        #pragma unroll
        for (int t = 0; t < 2; ++t)
            #pragma unroll
            for (int r = 0; r < 4; ++r) {
                int ml = wr * 32 + t * 16 + g * 4 + r;   // d
                float bi = bias[bo + ml];
                #pragma unroll
                for (int u = 0; u < 2; ++u) {
                    int nl = wc * 32 + u * 16 + c;       // 0..127
                    *(unsigned short*)(Ts + nl * 128 + ((ml * 2) ^ ((nl & 7) << 4))) =
                        f2bf((acc[pass][t][u][r] + bi) * esc);
                }
            }
        __syncthreads();
        #pragma unroll
        for (int i = 0; i < 2; ++i) {
            int idx = tid + i * 512;     // 1024 chunks = 128 rows x 8x16B
            int row = idx >> 3, ch = idx & 7;
            bf16x8 v = *(const bf16x8*)(Ts + row * 128 + ((ch * 16) ^ ((row & 7) << 4)));
            *(bf16x8*)&dst[((size_t)bh * N_DIM + nb + row) * HDIM + ch * 8] = v;
        }
    }
}

// ---------------------------------------------------------------------------
// conv_proj: out fp32 [b][c][n] + residual. (Unchanged.)
// ---------------------------------------------------------------------------
__global__ __launch_bounds__(256) void conv_proj(const unsigned short* __restrict__ Wb,
                                                 const float* __restrict__ bias,
                                                 const unsigned short* __restrict__ Bsrc,
                                                 const float* __restrict__ res,
                                                 float* __restrict__ outf) {
    __shared__ char smem[24576];
    int bn0 = blockIdx.x * 128;
    int bo  = blockIdx.y * 64;
    int tid = threadIdx.x;
    int L = tid & 63, w = tid >> 6;
    int g = L >> 4, c = L & 15;
    int wr = w >> 1, wc = w & 1;

    f32x4 acc[2][4];
    #pragma unroll
    for (int t = 0; t < 2; ++t)
        #pragma unroll
        for (int u = 0; u < 4; ++u) acc[t][u] = f32x4{0.f, 0.f, 0.f, 0.f};

    for (int k0 = 0; k0 < C_DIM; k0 += 64) {
        #pragma unroll
        for (int i = 0; i < 2; ++i) {
            int j = w * 2 + i;
            int ra = j * 8 + (L >> 3);
            int sl = (L & 7) ^ (ra & 7);
            GLL16(Wb + (size_t)(bo + ra) * C_DIM + k0 + sl * 8, smem + j * 1024);
        }
        #pragma unroll
        for (int i = 0; i < 4; ++i) {
            int j = w * 4 + i;
            int rb = j * 8 + (L >> 3);
            int sl = (L & 7) ^ (rb & 7);
            GLL16(Bsrc + (size_t)(bn0 + rb) * C_DIM + k0 + sl * 8, smem + 8192 + j * 1024);
        }
        __syncthreads();

        bf16x8 af[2][2], bfr[4][2];
        #pragma unroll
        for (int t = 0; t < 2; ++t) {
            int row = wr * 32 + t * 16 + c;
            #pragma unroll
            for (int ks = 0; ks < 2; ++ks)
                af[t][ks] = *(const bf16x8*)(smem + row * 128 +
                                             ((g * 16 + ks * 64) ^ ((row & 7) << 4)));
        }
        #pragma unroll
        for (int u = 0; u < 4; ++u) {
            int row = wc * 64 + u * 16 + c;
            #pragma unroll
            for (int ks = 0; ks < 2; ++ks)
                bfr[u][ks] = *(const bf16x8*)(smem + 8192 + row * 128 +
                                              ((g * 16 + ks * 64) ^ ((row & 7) << 4)));
        }
        #pragma unroll
        for (int ks = 0; ks < 2; ++ks)
            #pragma unroll
            for (int t = 0; t < 2; ++t)
                #pragma unroll
                for (int u = 0; u < 4; ++u)
                    acc[t][u] = __builtin_amdgcn_mfma_f32_16x16x32_bf16(
                        af[t][ks], bfr[u][ks], acc[t][u], 0, 0, 0);
        __syncthreads();
    }

    int b  = bn0 >> 11;
    int nb = bn0 & (N_DIM - 1);
    #pragma unroll
    for (int t = 0; t < 2; ++t)
        #pragma unroll
        for (int r = 0; r < 4; ++r) {
            int m = bo + wr * 32 + t * 16 + g * 4 + r;
            float bi = bias[m];
            #pragma unroll
            for (int u = 0; u < 4; ++u) {
                int n = nb + wc * 64 + u * 16 + c;
                size_t off = ((size_t)b * C_DIM + m) * N_DIM + n;
                outf[off] = acc[t][u][r] + bi + res[off];
            }
        }
}

// ---------------------------------------------------------------------------
// MFMA bf16 flash attention, swapped-operand form. 8 waves, QBLK=128.
// R17: T15 pipeline — 3 K/V buffers; per step: softmax(i)+P -> barrier ->
// stage(i+2) -> vmcnt(2) -> QK(i+1) interleaved with PV(i). EXP2R + XCD remap
// retained from R16.
// ---------------------------------------------------------------------------
__global__ __launch_bounds__(512, 4) void attn_kernel(const unsigned short* __restrict__ Qt,
                                                      const unsigned short* __restrict__ Kt,
                                                      const unsigned short* __restrict__ Vt,
                                                      unsigned short* __restrict__ at) {
    __shared__ char smem[65536];
    // [0,16K): Q staging -> P/O strips; [16K/32K/48K): buf0/1/2 (K 8K | V 8K)

    // ---- XCD-aware remap (grid = 512 linear blocks, XCD = d % 8) ----
    int d = blockIdx.x;                // 0..511 dispatch id
    int xcd = d & 7;
    int slot = d >> 3;                 // 0..63 within XCD
    int bh = xcd + 8 * (slot >> 4);    // heads {xcd, xcd+8, xcd+16, xcd+24}
    int q0 = (slot & 15) * 128;

    int b = bh >> 3, hh = bh & 7;
    int tid = threadIdx.x;
    int L = tid & 63, w = tid >> 6;        // 8 waves
    int g = L >> 4, c = L & 15;

    const unsigned short* Qh = Qt + (size_t)bh * N_DIM * HDIM;
    const unsigned short* Kh = Kt + (size_t)bh * N_DIM * HDIM;
    const unsigned short* Vh = Vt + (size_t)bh * HDIM * N_DIM;

    // ---- prologue: stage Q (16 x 1KB) + tiles 0,1 into buf0,buf1 ----
    #pragma unroll
    for (int i = 0; i < 2; ++i) {
        int j = w * 2 + i;
        int row = j * 8 + (L >> 3);        // 0..127
        int sl = (L & 7) ^ (row & 7);
        GLL16(Qh + (size_t)(q0 + row) * HDIM + sl * 8, smem + j * 1024);
    }
    int srow = w * 8 + (L >> 3);           // staging row 0..63
    int ssl  = (L & 7) ^ (srow & 7);
    GLL16(Kh + (size_t)srow * HDIM + ssl * 8,         smem + 16384 + w * 1024);
    GLL16(Vh + (size_t)srow * N_DIM + ssl * 8,        smem + 24576 + w * 1024);
    GLL16(Kh + (size_t)(64 + srow) * HDIM + ssl * 8,  smem + 32768 + w * 1024);
    GLL16(Vh + (size_t)srow * N_DIM + 64 + ssl * 8,   smem + 40960 + w * 1024);
    __syncthreads();                       // full drain: Q + tiles 0,1 ready

    // ---- hoisted addresses (buffer-relative; add boff at use) ----
    int csw = (c & 7) << 4;
    char* kb0 = smem + c * 128 + ((g * 16) ^ csw);        // K frag ks=0
    char* kb1 = smem + c * 128 + ((g * 16 + 64) ^ csw);   // K frag ks=1
    char* pb  = smem + (w * 16 + c) * 128;                // wave-private strip
    char* pw0 = pb + ((g * 8) ^ csw);
    char* pw1 = pb + ((32 + g * 8) ^ csw);
    char* pw2 = pb + ((64 + g * 8) ^ csw);
    char* pw3 = pb + ((96 + g * 8) ^ csw);
    char* pr0 = pb + ((g * 16) ^ csw);
    char* pr1 = pb + ((64 + g * 16) ^ csw);

    // Q fragments from strip region (same addresses as pr0/pr1)
    bf16x8 qf[2];
    qf[0] = *(const bf16x8*)pr0;
    qf[1] = *(const bf16x8*)pr1;

    // staging global pointers -> tile 2
    const unsigned short* kgp = Kh + (size_t)(128 + srow) * HDIM + ssl * 8;
    const unsigned short* vgp = Vh + (size_t)srow * N_DIM + 128 + ssl * 8;

    f32x4 oacc[4];
    #pragma unroll
    for (int t = 0; t < 4; ++t) oacc[t] = f32x4{0.f, 0.f, 0.f, 0.f};
    float m_r = -INFINITY, l_part = 0.f;

    // softmax on sCur -> P strip write (exp2 domain, zero-shfl steady state)
    auto smx = [&](f32x4 (&sacc)[4]) {
        float t0 = fmaxf(fmaxf(sacc[0][0], sacc[0][1]), sacc[0][2]);
        float t1 = fmaxf(fmaxf(sacc[0][3], sacc[1][0]), sacc[1][1]);
        float t2 = fmaxf(fmaxf(sacc[1][2], sacc[1][3]), sacc[2][0]);
        float t3 = fmaxf(fmaxf(sacc[2][1], sacc[2][2]), sacc[2][3]);
        float t4 = fmaxf(fmaxf(sacc[3][0], sacc[3][1]), sacc[3][2]);
        float mloc = fmaxf(fmaxf(fmaxf(t0, t1), fmaxf(t2, t3)), fmaxf(t4, sacc[3][3]));
        if (!__all(mloc - m_r <= 6.0f)) {       // rare: row max grew
            mloc = fmaxf(mloc, __shfl_xor(mloc, 16));
            mloc = fmaxf(mloc, __shfl_xor(mloc, 32));
            float mn = fmaxf(m_r, mloc);
            float fac = EXP2R(m_r - mn);
            m_r = mn;
            l_part *= fac;
            #pragma unroll
            for (int t = 0; t < 4; ++t) oacc[t] = oacc[t] * fac;
        }
        f32x4 m4 = {m_r, m_r, m_r, m_r};
        f32x4 p[4];
        #pragma unroll
        for (int t = 0; t < 4; ++t) {
            f32x4 dd = sacc[t] - m4;
            p[t][0] = EXP2R(dd[0]);
            p[t][1] = EXP2R(dd[1]);
            p[t][2] = EXP2R(dd[2]);
            p[t][3] = EXP2R(dd[3]);
        }
        f32x4 racc = (p[0] + p[1]) + (p[2] + p[3]);
        l_part += (racc[0] + racc[1]) + (racc[2] + racc[3]);

        unsigned pk[4][2];
        #pragma unroll
        for (int t = 0; t < 4; ++t) {
            pk[t][0] = BFPACK(p[t][0], p[t][1]);
            pk[t][1] = BFPACK(p[t][2], p[t][3]);
        }
        *(unsigned long long*)pw0 = (unsigned long long)pk[0][0] | ((unsigned long long)pk[0][1] << 32);
        *(unsigned long long*)pw1 = (unsigned long long)pk[1][0] | ((unsigned long long)pk[1][1] << 32);
        *(unsigned long long*)pw2 = (unsigned long long)pk[2][0] | ((unsigned long long)pk[2][1] << 32);
        *(unsigned long long*)pw3 = (unsigned long long)pk[3][0] | ((unsigned long long)pk[3][1] << 32);
    };

    // initial QK(0) from buf0
    f32x4 sA[4], sB[4];
    #pragma unroll
    for (int t = 0; t < 4; ++t) sA[t] = f32x4{0.f, 0.f, 0.f, 0.f};
    #pragma unroll
    for (int t = 0; t < 4; ++t) {
        bf16x8 kf0 = *(const bf16x8*)(kb0 + 16384 + t * 2048);
        bf16x8 kf1 = *(const bf16x8*)(kb1 + 16384 + t * 2048);
        sA[t] = __builtin_amdgcn_mfma_f32_16x16x32_bf16(kf0, qf[0], sA[t], 0, 0, 0);
        sA[t] = __builtin_amdgcn_mfma_f32_16x16x32_bf16(kf1, qf[1], sA[t], 0, 0, 0);
    }

    // step i: softmax(i) on sCur, stage(i+2) -> stoff (or -1), then
    // QK(i+1) -> sNxt (from kboff) interleaved with PV(i) (from vboff).
    auto step = [&](f32x4 (&sCur)[4], f32x4 (&sNxt)[4], int vboff, int kboff, int stoff) {
        smx(sCur);
        __builtin_amdgcn_s_barrier();
        asm volatile("" ::: "memory");
        if (stoff >= 0) {
            GLL16(kgp, smem + stoff + w * 1024);
            GLL16(vgp, smem + stoff + 8192 + w * 1024);
            kgp += 64 * HDIM;
            vgp += 64;
            asm volatile("s_waitcnt vmcnt(2)" ::: "memory");
        } else {
            asm volatile("s_waitcnt vmcnt(0)" ::: "memory");
        }
        __builtin_amdgcn_sched_barrier(0);

        __builtin_amdgcn_s_setprio(1);
        #pragma unroll
        for (int t = 0; t < 4; ++t) sNxt[t] = f32x4{0.f, 0.f, 0.f, 0.f};
        bf16x8 pf0 = *(const bf16x8*)pr0;
        bf16x8 pf1 = *(const bf16x8*)pr1;
        #pragma unroll
        for (int t = 0; t < 4; ++t) {
            bf16x8 kf0 = *(const bf16x8*)(kb0 + kboff + t * 2048);
            bf16x8 kf1 = *(const bf16x8*)(kb1 + kboff + t * 2048);
            sNxt[t] = __builtin_amdgcn_mfma_f32_16x16x32_bf16(kf0, qf[0], sNxt[t], 0, 0, 0);
            sNxt[t] = __builtin_amdgcn_mfma_f32_16x16x32_bf16(kf1, qf[1], sNxt[t], 0, 0, 0);
            bf16x8 vf0 = *(const bf16x8*)(kb0 + vboff + 8192 + t * 2048);
            bf16x8 vf1 = *(const bf16x8*)(kb1 + vboff + 8192 + t * 2048);
            oacc[t] = __builtin_amdgcn_mfma_f32_16x16x32_bf16(vf0, pf0, oacc[t], 0, 0, 0);
            oacc[t] = __builtin_amdgcn_mfma_f32_16x16x32_bf16(vf1, pf1, oacc[t], 0, 0, 0);
        }
        __builtin_amdgcn_s_setprio(0);
    };

    // buffers: tile i lives in buf[i%3]; rotation (vb,kb,st) <- (kb,st,vb)
    int vb = 16384, kb = 32768, st = 49152;
    for (int ii = 0; ii < 15; ++ii) {      // steps i = 0..29
        step(sA, sB, vb, kb, st);
        { int t_ = vb; vb = kb; kb = st; st = t_; }
        step(sB, sA, vb, kb, st);
        { int t_ = vb; vb = kb; kb = st; st = t_; }
    }
    // step i = 30: no staging (tile 32 doesn't exist)
    step(sA, sB, vb, kb, -1);
    { int t_ = vb; vb = kb; kb = st; st = t_; }
    // i = 31: final softmax + PV only (V from buf[31%3] = vb)
    {
        smx(sB);
        bf16x8 pf0 = *(const bf16x8*)pr0;
        bf16x8 pf1 = *(const bf16x8*)pr1;
        __builtin_amdgcn_s_setprio(1);
        #pragma unroll
        for (int t = 0; t < 4; ++t) {
            bf16x8 vf0 = *(const bf16x8*)(kb0 + vb + 8192 + t * 2048);
            bf16x8 vf1 = *(const bf16x8*)(kb1 + vb + 8192 + t * 2048);
            oacc[t] = __builtin_amdgcn_mfma_f32_16x16x32_bf16(vf0, pf0, oacc[t], 0, 0, 0);
            oacc[t] = __builtin_amdgcn_mfma_f32_16x16x32_bf16(vf1, pf1, oacc[t], 0, 0, 0);
        }
        __builtin_amdgcn_s_setprio(0);
    }

    // ---- deferred l reduction + epilogue (wave-private strip) ----
    float l_r = l_part;
    l_r += __shfl_xor(l_r, 16);
    l_r += __shfl_xor(l_r, 32);
    float oinv = __builtin_amdgcn_rcpf(l_r);
    {
        unsigned lo, hi;
        lo = BFPACK(oacc[0][0] * oinv, oacc[0][1] * oinv);
        hi = BFPACK(oacc[0][2] * oinv, oacc[0][3] * oinv);
        *(unsigned long long*)pw0 = (unsigned long long)lo | ((unsigned long long)hi << 32);
        lo = BFPACK(oacc[1][0] * oinv, oacc[1][1] * oinv);
        hi = BFPACK(oacc[1][2] * oinv, oacc[1][3] * oinv);
        *(unsigned long long*)pw1 = (unsigned long long)lo | ((unsigned long long)hi << 32);
        lo = BFPACK(oacc[2][0] * oinv, oacc[2][1] * oinv);
        hi = BFPACK(oacc[2][2] * oinv, oacc[2][3] * oinv);
        *(unsigned long long*)pw2 = (unsigned long long)lo | ((unsigned long long)hi << 32);
        lo = BFPACK(oacc[3][0] * oinv, oacc[3][1] * oinv);
        hi = BFPACK(oacc[3][2] * oinv, oacc[3][3] * oinv);
        *(unsigned long long*)pw3 = (unsigned long long)lo | ((unsigned long long)hi << 32);
    }
    char* wbase = smem + w * 2048;         // wave's 16 rows
    #pragma unroll
    for (int i = 0; i < 2; ++i) {
        int idx = L + i * 64;              // 128 chunks = 16 rows x 8x16B
        int row = idx >> 3, ch = idx & 7;
        bf16x8 v = *(const bf16x8*)(wbase + row * 128 + ((ch * 16) ^ ((row & 7) << 4)));
        *(bf16x8*)&at[((size_t)(b * N_DIM + q0 + w * 16 + row)) * C_DIM + hh * HDIM + ch * 8] = v;
    }
}

// ---------------------------------------------------------------------------
extern "C" void kernel_launch(void* const* d_in, const int* in_sizes, int n_in,
                              void* d_out, int out_size, void* d_ws, size_t ws_size,
                              hipStream_t stream) {
    (void)in_sizes; (void)n_in; (void)out_size; (void)ws_size;
    const float* x     = (const float*)d_in[0];
    const float* gam   = (const float*)d_in[1];
    const float* bet   = (const float*)d_in[2];
    const float* q_w   = (const float*)d_in[3];
    const float* q_b   = (const float*)d_in[4];
    const float* k_w   = (const float*)d_in[5];
    const float* k_b   = (const float*)d_in[6];
    const float* v_w   = (const float*)d_in[7];
    const float* v_b   = (const float*)d_in[8];
    const float* p_w   = (const float*)d_in[9];
    const float* p_b   = (const float*)d_in[10];
    float* out = (float*)d_out;

    const size_t MB = 1 << 20;
    char* wsb = (char*)d_ws;
    unsigned short* ht  = (unsigned short*)(wsb);              // 8 MB  [8192][512]
    unsigned short* wqb = (unsigned short*)(wsb + 8 * MB);     // 4 x 512KB contiguous (q,k,v,p)
    unsigned short* wpb = (unsigned short*)(wsb + 9 * MB + 512 * 1024);
    float*          partial = (float*)(wsb + 10 * MB);         // 2 KB
    unsigned short* qt  = (unsigned short*)(wsb + 11 * MB);    // 8 MB [bh][n][d]
    unsigned short* kt  = (unsigned short*)(wsb + 19 * MB);    // 8 MB
    unsigned short* vt  = (unsigned short*)(wsb + 27 * MB);    // 8 MB [b][c][n]
    unsigned short* at  = (unsigned short*)(wsb + 35 * MB);    // 8 MB [b][n][c]

    gn_stats<<<B_DIM * NGRP * 2, 256, 0, stream>>>(x, partial);
    gn_apply_t<<<dim3(N_DIM / 64, C_DIM / 64, B_DIM), 256, 0, stream>>>(x, partial, gam, bet, ht);

    cast4_bf16<<<dim3(128, 4), 256, 0, stream>>>(q_w, k_w, v_w, p_w, wqb);

    const float escale = 0.044194173824159216f * 1.4426950408889634f;  // scale*log2(e)
    conv_qkv<<<dim3(B_DIM * N_DIM / 128, C_DIM / 64), 512, 0, stream>>>(
        wqb, q_b, k_b, v_b, ht, qt, kt, vt, escale);

    attn_kernel<<<512, 512, 0, stream>>>(qt, kt, vt, at);

    conv_proj<<<dim3(B_DIM * N_DIM / 128, C_DIM / 64), 256, 0, stream>>>(wpb, p_b, at, x, out);
}